// Round 5
// baseline (895.045 us; speedup 1.0000x reference)
//
#include <hip/hip_runtime.h>
#include <cstdint>

// ---------------------------------------------------------------------------
// Types & helpers
// ---------------------------------------------------------------------------
typedef __attribute__((ext_vector_type(8))) short  bf16x8;   // 8 bf16 = 4 VGPR
typedef __attribute__((ext_vector_type(4))) float  f32x4;
typedef __attribute__((ext_vector_type(4))) unsigned int uint4v;
typedef __attribute__((ext_vector_type(2))) unsigned int uint2v;

typedef const __attribute__((address_space(1))) void* gas_t;
typedef __attribute__((address_space(3))) void* las_t;

__device__ __forceinline__ float bf2f(unsigned short b) {
    union { unsigned int u; float f; } v; v.u = ((unsigned int)b) << 16; return v.f;
}
__device__ __forceinline__ unsigned short f2bf(float f) {
    union { float f; unsigned int u; } v; v.f = f;
    unsigned int r = v.u + 0x7FFFu + ((v.u >> 16) & 1u);   // RNE
    return (unsigned short)(r >> 16);
}

// ---------------------------------------------------------------------------
// RMSNorm: fp32 [T,4096] -> bf16 [T,4096]
// ---------------------------------------------------------------------------
__global__ __launch_bounds__(256)
void rmsnorm_kernel(const float* __restrict__ x, const float* __restrict__ wgt,
                    unsigned short* __restrict__ out)
{
    const int t = blockIdx.x, tid = threadIdx.x;
    const float4* xr = (const float4*)(x + (size_t)t * 4096);
    float4 v[4];
    float ss = 0.f;
#pragma unroll
    for (int j = 0; j < 4; j++) {
        v[j] = xr[(j << 8) + tid];
        ss += v[j].x*v[j].x + v[j].y*v[j].y + v[j].z*v[j].z + v[j].w*v[j].w;
    }
#pragma unroll
    for (int m = 1; m < 64; m <<= 1) ss += __shfl_xor(ss, m);
    __shared__ float red[4];
    if ((tid & 63) == 0) red[tid >> 6] = ss;
    __syncthreads();
    float tot = red[0] + red[1] + red[2] + red[3];
    float rs = rsqrtf(tot * (1.f / 4096.f) + 1e-6f);
    const float4* wr = (const float4*)wgt;
#pragma unroll
    for (int j = 0; j < 4; j++) {
        float4 wv = wr[(j << 8) + tid];
        float4 xv = v[j];
        unsigned int p0 = (unsigned int)f2bf(xv.x*rs*wv.x) | ((unsigned int)f2bf(xv.y*rs*wv.y) << 16);
        unsigned int p1 = (unsigned int)f2bf(xv.z*rs*wv.z) | ((unsigned int)f2bf(xv.w*rs*wv.w) << 16);
        uint2v pk = {p0, p1};
        *(uint2v*)(&out[(size_t)t*4096 + (size_t)(((j << 8) + tid) << 2)]) = pk;
    }
}

// ---------------------------------------------------------------------------
// AWQ GEMM: C[1024,N] = A[1024,K](bf16) @ dequant(qw,qz,sc)[K,N]
// Tile TM x TN, BK=64.
//   TM=256,TN=256: 512 thr, 8 waves (2M x 4N), wave-tile 128x64 (m201 geom)
//   TM=128,TN=128: 256 thr, 4 waves (2M x 2N), wave-tile 64x64
// Counted-waitcnt pipeline (R4):
//   STAGE(t+1) async global_load_lds  (stays in flight)
//   dequant(t) Bqs->Bs                 (LDS+VALU)
//   lgkmcnt(0) + s_barrier + sched_barrier   <- vmcnt NOT drained
//   setprio(1)  MFMA(t)  setprio(0)
//   vmcnt(0) + s_barrier                <- loads had dequant+MFMA to fly
// MODE 0: bf16 out. MODE 1: dual weight-set (blockIdx.z). MODE 3: f32 +res.
// ---------------------------------------------------------------------------
template<int MODE, int TM, int TN>
__global__ __launch_bounds__(TM + TN, 2)
void awq_gemm(const unsigned short* __restrict__ A,
              const int* __restrict__ qw0, const int* __restrict__ qz0, const float* __restrict__ sc0,
              const int* __restrict__ qw1, const int* __restrict__ qz1, const float* __restrict__ sc1,
              void* __restrict__ out0, void* __restrict__ out1,
              const float* __restrict__ res,
              int N, int K)
{
    constexpr int NTHR    = TM + TN;                 // 512 or 256
    constexpr int NWAVES  = NTHR / 64;
    constexpr int WAVES_N = (TN == 256) ? 4 : 2;
    constexpr int WTM     = TM / (NWAVES / WAVES_N); // 128 or 64
    constexpr int MI      = WTM / 16;                // 8 or 4
    constexpr int ASHOTS  = (TM * 8) / NTHR;         // 4
    constexpr int BQW     = TN / 8;                  // packed words per k-row
    constexpr int KGH_SH  = (TN == 256) ? 8 : 7;

    __shared__ unsigned short As[2][TM * 64];        // 2 x TM*128B
    __shared__ unsigned int   Bqs[2][64 * BQW];      // packed words
    __shared__ unsigned short Bs[TN * 64];           // dequanted B^T [n][k]

    const int tid  = threadIdx.x;
    const int lane = tid & 63;
    const int wid  = tid >> 6;
    const int wm   = wid / WAVES_N, wn = wid % WAVES_N;
    const int m0   = blockIdx.y * TM;
    const int n0   = blockIdx.x * TN;
    const int NW   = N >> 3;

    const int* qw = qw0; const int* qz = qz0; const float* sc = sc0;
    void* outp = out0;
    if (MODE == 1 && blockIdx.z == 1) { qw = qw1; qz = qz1; sc = sc1; outp = out1; }

    // dequant duty: col bc, k-groups (kgh*4 .. kgh*4+3), 8 k each
    const int bc   = tid & (TN - 1);
    const int kgh  = tid >> KGH_SH;                  // 0/1
    const int gn   = n0 + bc;
    const int nsh  = (bc & 7) << 2;
    const int gwc0 = n0 >> 3;

    f32x4 acc[MI][4];
#pragma unroll
    for (int i = 0; i < MI; i++)
#pragma unroll
        for (int j = 0; j < 4; j++) { f32x4 zv = {0.f,0.f,0.f,0.f}; acc[i][j] = zv; }

    float sc_pf; unsigned int zw_pf;

    auto stage = [&](int t, int buf) {
        const int k0 = t << 6;
        // A tile TMx64: source pre-swizzled, LDS linear
#pragma unroll
        for (int i = 0; i < ASHOTS; i++) {
            int slot = i * NTHR + tid;
            int row = slot >> 3, s = slot & 7;
            const unsigned short* g = A + (size_t)(m0 + row) * K + k0 + ((s ^ (row & 7)) << 3);
            __builtin_amdgcn_global_load_lds((gas_t)g,
                (las_t)&As[buf][(i * NTHR + (wid << 6)) << 3], 16, 0, 0);
        }
        // B packed words 64 x BQW, coalesced dwordx4
        {
            const int kr = tid / (BQW >> 2);
            const int jc = (tid % (BQW >> 2)) << 2;
            const int* gq = qw + (size_t)(k0 + kr) * NW + gwc0 + jc;
            __builtin_amdgcn_global_load_lds((gas_t)gq,
                (las_t)&Bqs[buf][wid << 8], 16, 0, 0);
        }
    };

    auto ldsz = [&](int t) {
        int g = t >> 1;   // (t*64)/128
        sc_pf = sc[(size_t)g * N + gn];
        zw_pf = (unsigned int)qz[(size_t)g * NW + (gn >> 3)];
    };

    auto dequant = [&](int buf) {
        const float scale = sc_pf;
        const float nzs = -(float)((zw_pf >> nsh) & 0xFu) * scale;
#pragma unroll
        for (int j = 0; j < 4; j++) {
            int kg = (kgh << 2) + j;
            const unsigned int* bq = &Bqs[buf][kg * (BQW << 3) + (bc >> 3)];
            unsigned int wv[8];
#pragma unroll
            for (int i = 0; i < 8; i++) wv[i] = bq[i * BQW];
            unsigned int pk[4];
#pragma unroll
            for (int i = 0; i < 4; i++) {
                float f0 = (float)((wv[2*i]   >> nsh) & 0xFu) * scale + nzs;
                float f1 = (float)((wv[2*i+1] >> nsh) & 0xFu) * scale + nzs;
                asm("v_cvt_pk_bf16_f32 %0, %1, %2" : "=v"(pk[i]) : "v"(f0), "v"(f1));
            }
            int s = kg ^ (bc & 7);
            uint4v bvv = {pk[0], pk[1], pk[2], pk[3]};
            *(uint4v*)(&Bs[(bc << 6) + (s << 3)]) = bvv;
        }
    };

    const int nsteps = K >> 6;
    stage(0, 0);
    ldsz(0);
    asm volatile("s_waitcnt vmcnt(0)" ::: "memory");
    __builtin_amdgcn_s_barrier();
    __builtin_amdgcn_sched_barrier(0);

    int cur = 0;
    for (int t = 0; t < nsteps; t++) {
        if (t + 1 < nsteps) stage(t + 1, cur ^ 1);   // async, flies over dequant+MFMA
        dequant(cur);
        if (t + 1 < nsteps) ldsz(t + 1);             // plain loads, fly during MFMA
        asm volatile("s_waitcnt lgkmcnt(0)" ::: "memory");
        __builtin_amdgcn_s_barrier();                // Bs visible; vmcnt untouched
        __builtin_amdgcn_sched_barrier(0);
        __builtin_amdgcn_s_setprio(1);
#pragma unroll
        for (int kk = 0; kk < 2; kk++) {
            const int srow = (kk << 2) + (lane >> 4);
            bf16x8 af[MI], bfv[4];
#pragma unroll
            for (int mi = 0; mi < MI; mi++) {
                int r = wm * WTM + (mi << 4) + (lane & 15);
                af[mi] = *(const bf16x8*)(&As[cur][(r << 6) + ((srow ^ (r & 7)) << 3)]);
            }
#pragma unroll
            for (int ni = 0; ni < 4; ni++) {
                int r = (wn << 6) + (ni << 4) + (lane & 15);
                bfv[ni] = *(const bf16x8*)(&Bs[(r << 6) + ((srow ^ (r & 7)) << 3)]);
            }
#pragma unroll
            for (int mi = 0; mi < MI; mi++)
#pragma unroll
                for (int ni = 0; ni < 4; ni++)
                    acc[mi][ni] = __builtin_amdgcn_mfma_f32_16x16x32_bf16(af[mi], bfv[ni], acc[mi][ni], 0, 0, 0);
        }
        __builtin_amdgcn_s_setprio(0);
        asm volatile("s_waitcnt vmcnt(0)" ::: "memory");   // t+1 tiles landed
        __builtin_amdgcn_s_barrier();
        __builtin_amdgcn_sched_barrier(0);
        cur ^= 1;
    }

    // epilogue: C/D layout col=lane&15, row=(lane>>4)*4+reg
    const int rbase = m0 + wm * WTM + ((lane >> 4) << 2);
    const int cbase = n0 + (wn << 6) + (lane & 15);
#pragma unroll
    for (int mi = 0; mi < MI; mi++) {
#pragma unroll
        for (int r = 0; r < 4; r++) {
            int row = rbase + (mi << 4) + r;
#pragma unroll
            for (int ni = 0; ni < 4; ni++) {
                int col = cbase + (ni << 4);
                float v = acc[mi][ni][r];
                if (MODE == 0 || MODE == 1) {
                    ((unsigned short*)outp)[(size_t)row * N + col] = f2bf(v);
                } else {
                    ((float*)out0)[(size_t)row * N + col] = v + res[(size_t)row * N + col];
                }
            }
        }
    }
}

// ---------------------------------------------------------------------------
// RoPE + layout glue: qkv bf16 [T,12288] ->
//   Qr [32][1024][128] (pre-scaled by 1/sqrt(128)), Kr [32][1024][128],
//   Vt [32][128][1024] (transposed V)
// ---------------------------------------------------------------------------
__global__ __launch_bounds__(256)
void rope_kernel(const int* __restrict__ positions, const unsigned short* __restrict__ qkv,
                 unsigned short* __restrict__ Qr, unsigned short* __restrict__ Kr,
                 unsigned short* __restrict__ Vtp)
{
    const int t = blockIdx.x, tid = threadIdx.x;
    const float p = (float)positions[t];
    const unsigned short* row = qkv + (size_t)t * 12288;
#pragma unroll 4
    for (int it = 0; it < 16; it++) {
        int task = (it << 8) + tid;
        int i   = task & 63;
        int hh  = (task >> 6) & 31;
        int isK = task >> 11;
        float fr = p * __expf(-(float)i * 0.14391156831f);
        float s, c;
        __sincosf(fr, &s, &c);
        const unsigned short* src = row + (isK << 12) + (hh << 7);
        float x1 = bf2f(src[i]);
        float x2 = bf2f(src[64 + i]);
        float o1 = x1 * c - x2 * s;
        float o2 = x2 * c + x1 * s;
        if (!isK) { o1 *= 0.08838834764831845f; o2 *= 0.08838834764831845f; }
        unsigned short* dst = (isK ? Kr : Qr) + ((size_t)hh * 1024 + t) * 128;
        dst[i]      = f2bf(o1);
        dst[64 + i] = f2bf(o2);
    }
#pragma unroll 4
    for (int it = 0; it < 16; it++) {
        int task = (it << 8) + tid;
        int d = task & 127, hh = task >> 7;
        Vtp[((size_t)hh * 128 + d) * 1024 + t] = row[8192 + task];
    }
}

// ---------------------------------------------------------------------------
// Flash attention (causal). Block = (qt, head). 4 waves x 16 q-rows.
// ---------------------------------------------------------------------------
__global__ __launch_bounds__(256, 2)
void attn_kernel(const unsigned short* __restrict__ Qr, const unsigned short* __restrict__ Kr,
                 const unsigned short* __restrict__ Vtp, unsigned short* __restrict__ attn_out)
{
    __shared__ unsigned short Ks[64 * 128];
    __shared__ unsigned short Vs[128 * 64];
    __shared__ unsigned short Ps[4][16 * 64];
    const int tid = threadIdx.x, lane = tid & 63, w = tid >> 6;
    const int qt = blockIdx.x, h = blockIdx.y;

    const unsigned short* Qh = Qr + ((size_t)h * 1024 + (size_t)qt * 64) * 128;

    bf16x8 qf[4];
#pragma unroll
    for (int kk = 0; kk < 4; kk++)
        qf[kk] = *(const bf16x8*)(Qh + (size_t)((w << 4) + (lane & 15)) * 128 + (kk << 5) + ((lane >> 4) << 3));

    f32x4 o[8];
#pragma unroll
    for (int i = 0; i < 8; i++) { f32x4 zf = {0.f,0.f,0.f,0.f}; o[i] = zf; }
    float Mr[4] = {-1e30f, -1e30f, -1e30f, -1e30f};
    float Lr[4] = {0.f, 0.f, 0.f, 0.f};
    const int qrow0 = (qt << 6) + (w << 4) + ((lane >> 4) << 2);

    for (int kt = 0; kt <= qt; kt++) {
        __syncthreads();
#pragma unroll
        for (int j = 0; j < 4; j++) {
            int slot = (j << 8) + tid;
            int rw = slot >> 4, s = slot & 15;
            int ssrc = (s & 8) | ((s ^ (rw & 7)) & 7);
            const uint4v* src = (const uint4v*)(Kr + ((size_t)h * 1024 + (size_t)kt * 64 + rw) * 128 + (ssrc << 3));
            *(uint4v*)(&Ks[(rw << 7) + (s << 3)]) = *src;
        }
#pragma unroll
        for (int j = 0; j < 4; j++) {
            int slot = (j << 8) + tid;
            int rw = slot >> 3, s = slot & 7;
            const uint4v* src = (const uint4v*)(Vtp + ((size_t)h * 128 + rw) * 1024 + (kt << 6) + ((s ^ (rw & 7)) << 3));
            *(uint4v*)(&Vs[(rw << 6) + (s << 3)]) = *src;
        }
        __syncthreads();

        f32x4 sc4[4];
#pragma unroll
        for (int ni = 0; ni < 4; ni++) { f32x4 zf = {0.f,0.f,0.f,0.f}; sc4[ni] = zf; }
#pragma unroll
        for (int kk = 0; kk < 4; kk++) {
#pragma unroll
            for (int ni = 0; ni < 4; ni++) {
                int r = (ni << 4) + (lane & 15);
                int s = (kk << 2) + (lane >> 4);
                int sp = (s & 8) | ((s ^ (r & 7)) & 7);
                bf16x8 kf = *(const bf16x8*)(&Ks[(r << 7) + (sp << 3)]);
                sc4[ni] = __builtin_amdgcn_mfma_f32_16x16x32_bf16(qf[kk], kf, sc4[ni], 0, 0, 0);
            }
        }

#pragma unroll
        for (int r = 0; r < 4; r++) {
            int qg = qrow0 + r;
            float mx = -1e30f;
#pragma unroll
            for (int ni = 0; ni < 4; ni++) {
                int kg_ = (kt << 6) + (ni << 4) + (lane & 15);
                float v = sc4[ni][r];
                if (kt == qt && kg_ > qg) { v = -1e30f; sc4[ni][r] = v; }
                mx = fmaxf(mx, v);
            }
#pragma unroll
            for (int m_ = 1; m_ < 16; m_ <<= 1) mx = fmaxf(mx, __shfl_xor(mx, m_));
            float mnew  = fmaxf(Mr[r], mx);
            float alpha = __expf(Mr[r] - mnew);
            Mr[r] = mnew;
            float rs = 0.f;
#pragma unroll
            for (int ni = 0; ni < 4; ni++) {
                float pv = __expf(sc4[ni][r] - mnew);
                sc4[ni][r] = pv;
                rs += pv;
            }
#pragma unroll
            for (int m_ = 1; m_ < 16; m_ <<= 1) rs += __shfl_xor(rs, m_);
            Lr[r] = Lr[r] * alpha + rs;
#pragma unroll
            for (int nd = 0; nd < 8; nd++) o[nd][r] *= alpha;
        }

#pragma unroll
        for (int r = 0; r < 4; r++) {
            int qr = ((lane >> 4) << 2) + r;
#pragma unroll
            for (int ni = 0; ni < 4; ni++) {
                int col = (ni << 4) + (lane & 15);
                int phys = (col >> 3) ^ (qr & 7);
                Ps[w][(qr << 6) + (phys << 3) + (col & 7)] = f2bf(sc4[ni][r]);
            }
        }
#pragma unroll
        for (int kk2 = 0; kk2 < 2; kk2++) {
            int rowp = lane & 15;
            int sl = (kk2 << 2) + (lane >> 4);
            bf16x8 pa = *(const bf16x8*)(&Ps[w][(rowp << 6) + ((sl ^ (rowp & 7)) << 3)]);
#pragma unroll
            for (int nd = 0; nd < 8; nd++) {
                int rv = (nd << 4) + (lane & 15);
                bf16x8 vb = *(const bf16x8*)(&Vs[(rv << 6) + ((sl ^ (rv & 7)) << 3)]);
                o[nd] = __builtin_amdgcn_mfma_f32_16x16x32_bf16(pa, vb, o[nd], 0, 0, 0);
            }
        }
    }

#pragma unroll
    for (int r = 0; r < 4; r++) {
        float inv = 1.0f / Lr[r];
        int trow = qrow0 + r;
#pragma unroll
        for (int nd = 0; nd < 8; nd++) {
            int col = (h << 7) + (nd << 4) + (lane & 15);
            attn_out[(size_t)trow * 4096 + col] = f2bf(o[nd][r] * inv);
        }
    }
}

// ---------------------------------------------------------------------------
// silu(gate) * up, bf16, in-place into `up` (recomputed each call)
// ---------------------------------------------------------------------------
__global__ __launch_bounds__(256)
void silu_mul_kernel(const unsigned short* __restrict__ gate, unsigned short* __restrict__ up)
{
    size_t idx = ((size_t)blockIdx.x * 256 + threadIdx.x) * 8;
    uint4v g = *(const uint4v*)(gate + idx);
    uint4v u = *(const uint4v*)(up + idx);
    unsigned int outp[4];
#pragma unroll
    for (int j = 0; j < 4; j++) {
        unsigned int gw = g[j], uw = u[j];
        float g0 = bf2f((unsigned short)(gw & 0xFFFF)), g1 = bf2f((unsigned short)(gw >> 16));
        float u0 = bf2f((unsigned short)(uw & 0xFFFF)), u1 = bf2f((unsigned short)(uw >> 16));
        float s0 = g0 / (1.f + __expf(-g0)) * u0;
        float s1 = g1 / (1.f + __expf(-g1)) * u1;
        outp[j] = (unsigned int)f2bf(s0) | ((unsigned int)f2bf(s1) << 16);
    }
    uint4v ov = {outp[0], outp[1], outp[2], outp[3]};
    *(uint4v*)(up + idx) = ov;
}

// ---------------------------------------------------------------------------
// Launcher
// ---------------------------------------------------------------------------
extern "C" void kernel_launch(void* const* d_in, const int* in_sizes, int n_in,
                              void* d_out, int out_size, void* d_ws, size_t ws_size,
                              hipStream_t stream)
{
    const int*   positions = (const int*)  d_in[0];
    const float* hidden    = (const float*)d_in[1];
    const float* ln1       = (const float*)d_in[2];
    const float* ln2       = (const float*)d_in[3];
    const int*   qkv_qw    = (const int*)  d_in[4];
    const int*   qkv_qz    = (const int*)  d_in[5];
    const float* qkv_sc    = (const float*)d_in[6];
    const int*   o_qw      = (const int*)  d_in[7];
    const int*   o_qz      = (const int*)  d_in[8];
    const float* o_sc      = (const float*)d_in[9];
    const int*   gate_qw   = (const int*)  d_in[10];
    const int*   gate_qz   = (const int*)  d_in[11];
    const float* gate_sc   = (const float*)d_in[12];
    const int*   up_qw     = (const int*)  d_in[13];
    const int*   up_qz     = (const int*)  d_in[14];
    const float* up_sc     = (const float*)d_in[15];
    const int*   down_qw   = (const int*)  d_in[16];
    const int*   down_qz   = (const int*)  d_in[17];
    const float* down_sc   = (const float*)d_in[18];

    char* ws = (char*)d_ws;
    unsigned short* xln   = (unsigned short*)(ws + 0);          //  8.39 MB [T,H] bf16
    unsigned short* qkvb  = (unsigned short*)(ws + 8388608);    // 25.17 MB [T,3H] bf16
    unsigned short* Qrp   = (unsigned short*)(ws + 33554432);   //  8.39 MB
    unsigned short* Krp   = (unsigned short*)(ws + 41943040);   //  8.39 MB
    unsigned short* Vtp   = (unsigned short*)(ws + 50331648);   //  8.39 MB
    unsigned short* attnb = (unsigned short*)(ws + 58720256);   //  8.39 MB [T,H] bf16
    float*          hid   = (float*)        (ws + 67108864);    // 16.78 MB [T,H] f32
    unsigned short* x2    = (unsigned short*)(ws + 0);          // reuse xln
    unsigned short* gateb = (unsigned short*)(ws + 8388608);    // reuse qkvb
    unsigned short* upb   = (unsigned short*)(ws + 33554432);   // reuse Q/K/V

    // --- attention block ---
    rmsnorm_kernel<<<1024, 256, 0, stream>>>(hidden, ln1, xln);
    awq_gemm<0, 256, 256><<<dim3(48, 4), 512, 0, stream>>>(xln, qkv_qw, qkv_qz, qkv_sc,
                                                           nullptr, nullptr, nullptr,
                                                           (void*)qkvb, nullptr, nullptr,
                                                           12288, 4096);
    rope_kernel<<<1024, 256, 0, stream>>>(positions, qkvb, Qrp, Krp, Vtp);
    attn_kernel<<<dim3(16, 32), 256, 0, stream>>>(Qrp, Krp, Vtp, attnb);
    awq_gemm<3, 128, 128><<<dim3(32, 8), 256, 0, stream>>>(attnb, o_qw, o_qz, o_sc,
                                                           nullptr, nullptr, nullptr,
                                                           (void*)hid, nullptr, hidden,
                                                           4096, 4096);
    // --- MLP block ---
    rmsnorm_kernel<<<1024, 256, 0, stream>>>(hid, ln2, x2);
    awq_gemm<1, 256, 256><<<dim3(43, 4, 2), 512, 0, stream>>>(x2, gate_qw, gate_qz, gate_sc,
                                                              up_qw, up_qz, up_sc,
                                                              (void*)gateb, (void*)upb, nullptr,
                                                              11008, 4096);
    silu_mul_kernel<<<5504, 256, 0, stream>>>(gateb, upb);
    awq_gemm<3, 128, 128><<<dim3(32, 8), 256, 0, stream>>>(upb, down_qw, down_qz, down_sc,
                                                           nullptr, nullptr, nullptr,
                                                           d_out, nullptr, hid,
                                                           4096, 11008);
}

// Round 6
// 846.233 us; speedup vs baseline: 1.0577x; 1.0577x over previous
//
#include <hip/hip_runtime.h>
#include <cstdint>

// ---------------------------------------------------------------------------
// Types & helpers
// ---------------------------------------------------------------------------
typedef __attribute__((ext_vector_type(8))) short  bf16x8;   // 8 bf16 = 4 VGPR
typedef __attribute__((ext_vector_type(4))) float  f32x4;
typedef __attribute__((ext_vector_type(4))) unsigned int uint4v;
typedef __attribute__((ext_vector_type(2))) unsigned int uint2v;

typedef const __attribute__((address_space(1))) void* gas_t;
typedef __attribute__((address_space(3))) void* las_t;

__device__ __forceinline__ float bf2f(unsigned short b) {
    union { unsigned int u; float f; } v; v.u = ((unsigned int)b) << 16; return v.f;
}
__device__ __forceinline__ unsigned short f2bf(float f) {
    union { float f; unsigned int u; } v; v.f = f;
    unsigned int r = v.u + 0x7FFFu + ((v.u >> 16) & 1u);   // RNE
    return (unsigned short)(r >> 16);
}
__device__ __forceinline__ float u2f(unsigned int u) {
    union { unsigned int u; float f; } v; v.u = u; return v.f;
}

// ---------------------------------------------------------------------------
// RMSNorm: fp32 [T,4096] -> bf16 [T,4096]
// ---------------------------------------------------------------------------
__global__ __launch_bounds__(256)
void rmsnorm_kernel(const float* __restrict__ x, const float* __restrict__ wgt,
                    unsigned short* __restrict__ out)
{
    const int t = blockIdx.x, tid = threadIdx.x;
    const float4* xr = (const float4*)(x + (size_t)t * 4096);
    float4 v[4];
    float ss = 0.f;
#pragma unroll
    for (int j = 0; j < 4; j++) {
        v[j] = xr[(j << 8) + tid];
        ss += v[j].x*v[j].x + v[j].y*v[j].y + v[j].z*v[j].z + v[j].w*v[j].w;
    }
#pragma unroll
    for (int m = 1; m < 64; m <<= 1) ss += __shfl_xor(ss, m);
    __shared__ float red[4];
    if ((tid & 63) == 0) red[tid >> 6] = ss;
    __syncthreads();
    float tot = red[0] + red[1] + red[2] + red[3];
    float rs = rsqrtf(tot * (1.f / 4096.f) + 1e-6f);
    const float4* wr = (const float4*)wgt;
#pragma unroll
    for (int j = 0; j < 4; j++) {
        float4 wv = wr[(j << 8) + tid];
        float4 xv = v[j];
        unsigned int p0 = (unsigned int)f2bf(xv.x*rs*wv.x) | ((unsigned int)f2bf(xv.y*rs*wv.y) << 16);
        unsigned int p1 = (unsigned int)f2bf(xv.z*rs*wv.z) | ((unsigned int)f2bf(xv.w*rs*wv.w) << 16);
        uint2v pk = {p0, p1};
        *(uint2v*)(&out[(size_t)t*4096 + (size_t)(((j << 8) + tid) << 2)]) = pk;
    }
}

// ---------------------------------------------------------------------------
// AWQ GEMM, m201-style 4-phase schedule.
// C[1024,N] = A[1024,K](bf16) @ dequant(qw,qz,sc)[K,N]
// Tile 256x256, BK=64, 512 thr = 8 waves (2M x 4N), wave-tile 128x64.
// LDS: As dbuf 2x32KB + Bs dbuf 2x32KB = 128KB -> 1 blk/CU (by design).
// Per K-step: 4 phases, each {ds_reads | stage issues} bar lgk(0) SB
//             prio1 16xMFMA prio0 bar.  Single vmcnt(0) at P3 (3 phases of
//             flight for staging).  B words: direct global->reg (no LDS
//             roundtrip); dequant(t+1) in P3 -> swizzled ds_write to Bs[nxt].
// MODE 0: bf16 out. MODE 1: dual weight-set (z). MODE 2: split-K, bf16
//         partial at z*1024*N.
// ---------------------------------------------------------------------------
template<int MODE>
__global__ __launch_bounds__(512, 2)
void awq_gemm(const unsigned short* __restrict__ A,
              const int* __restrict__ qw0, const int* __restrict__ qz0, const float* __restrict__ sc0,
              const int* __restrict__ qw1, const int* __restrict__ qz1, const float* __restrict__ sc1,
              void* __restrict__ out0, void* __restrict__ out1,
              int N, int K, int ksplit)
{
    __shared__ unsigned short As[2][256 * 64];   // 2 x 32KB (16B-slot XOR swizzle)
    __shared__ unsigned short Bs[2][256 * 64];   // 2 x 32KB  B^T [n][k] swizzled

    const int tid  = threadIdx.x;
    const int lane = tid & 63;
    const int wid  = tid >> 6;
    const int wm   = wid >> 2, wn = wid & 3;     // 2M x 4N
    const int m0   = blockIdx.y << 8;
    const int n0   = blockIdx.x << 8;
    const int z    = blockIdx.z;
    const int NW   = N >> 3;

    const int* qw = qw0; const int* qz = qz0; const float* sc = sc0;
    void* outp = out0;
    if (MODE == 1 && z == 1) { qw = qw1; qz = qz1; sc = sc1; outp = out1; }
    const int k0base = (MODE == 2) ? z * ksplit : 0;
    const int nsteps = ((MODE == 2) ? ksplit : K) >> 6;

    // dequant duty: col bc (one n), k-half kgh (32 k)
    const int bc  = tid & 255;
    const int kgh = tid >> 8;                    // 0/1
    const int gn  = n0 + bc;
    const int nsh = (bc & 7) << 2;
    const int wcg = gn >> 3;

    f32x4 acc[8][4];
#pragma unroll
    for (int i = 0; i < 8; i++)
#pragma unroll
        for (int j = 0; j < 4; j++) { f32x4 zv = {0.f,0.f,0.f,0.f}; acc[i][j] = zv; }

    unsigned int w_pf[32];
    float sc_pf; unsigned int zw_pf;
    int cur = 0;

    auto stageA = [&](int t, int buf) {
        const int k0 = k0base + (t << 6);
#pragma unroll
        for (int i = 0; i < 4; i++) {
            int slot = (i << 9) + tid;
            int row = slot >> 3, s = slot & 7;
            const unsigned short* g = A + (size_t)(m0 + row) * K + k0 + ((s ^ (row & 7)) << 3);
            __builtin_amdgcn_global_load_lds((gas_t)g,
                (las_t)&As[buf][((i << 9) + (wid << 6)) << 3], 16, 0, 0);
        }
    };
    auto load_words = [&](int t, int h) {
        const int k0 = k0base + (t << 6) + (kgh << 5) + (h << 4);
        const int* gq = qw + (size_t)k0 * NW + wcg;
#pragma unroll
        for (int i = 0; i < 16; i++) w_pf[(h << 4) + i] = (unsigned int)gq[(size_t)i * NW];
    };
    auto ldsz = [&](int t) {
        int g = (k0base + (t << 6)) >> 7;
        sc_pf = sc[(size_t)g * N + gn];
        zw_pf = (unsigned int)qz[(size_t)g * NW + wcg];
    };
    auto dequant = [&](int buf) {
        const float scale = sc_pf;
        const float moff = -(8388608.0f + (float)((zw_pf >> nsh) & 0xFu)) * scale;
#pragma unroll
        for (int j = 0; j < 4; j++) {
            unsigned int pk[4];
#pragma unroll
            for (int i = 0; i < 4; i++) {
                float f0 = fmaf(u2f(((w_pf[j*8+2*i]   >> nsh) & 0xFu) | 0x4B000000u), scale, moff);
                float f1 = fmaf(u2f(((w_pf[j*8+2*i+1] >> nsh) & 0xFu) | 0x4B000000u), scale, moff);
                asm("v_cvt_pk_bf16_f32 %0, %1, %2" : "=v"(pk[i]) : "v"(f0), "v"(f1));
            }
            int kg = (kgh << 2) + j;
            int s = kg ^ (bc & 7);
            uint4v bvv = {pk[0], pk[1], pk[2], pk[3]};
            *(uint4v*)(&Bs[buf][(bc << 6) + (s << 3)]) = bvv;
        }
    };
    auto ldsA = [&](int kk, int mh, bf16x8* af) {
        const int srow = (kk << 2) + (lane >> 4);
#pragma unroll
        for (int mi = 0; mi < 4; mi++) {
            int r = (wm << 7) + (((mh << 2) + mi) << 4) + (lane & 15);
            af[mi] = *(const bf16x8*)(&As[cur][(r << 6) + ((srow ^ (r & 7)) << 3)]);
        }
    };
    auto ldsB = [&](int kk, bf16x8* bfv) {
        const int srow = (kk << 2) + (lane >> 4);
#pragma unroll
        for (int ni = 0; ni < 4; ni++) {
            int r = (wn << 6) + (ni << 4) + (lane & 15);
            bfv[ni] = *(const bf16x8*)(&Bs[cur][(r << 6) + ((srow ^ (r & 7)) << 3)]);
        }
    };

    // ---- prologue: tile 0
    stageA(0, 0);
    load_words(0, 0); load_words(0, 1); ldsz(0);
    asm volatile("s_waitcnt vmcnt(0)" ::: "memory");
    __builtin_amdgcn_sched_barrier(0);
    dequant(0);
    asm volatile("s_waitcnt lgkmcnt(0)" ::: "memory");
    __builtin_amdgcn_s_barrier();

    for (int t = 0; t < nsteps; t++) {
        const bool pf = (t + 1 < nsteps);
        bf16x8 af[4], bfv0[4], bfv1[4];
        // ---------- P0: stage A(t+1) + words half 0; frags kk0
        if (pf) { stageA(t + 1, cur ^ 1); load_words(t + 1, 0); ldsz(t + 1); }
        ldsB(0, bfv0); ldsA(0, 0, af);
        __builtin_amdgcn_s_barrier();
        asm volatile("s_waitcnt lgkmcnt(0)" ::: "memory");
        __builtin_amdgcn_sched_barrier(0);
        __builtin_amdgcn_s_setprio(1);
#pragma unroll
        for (int mi = 0; mi < 4; mi++)
#pragma unroll
            for (int ni = 0; ni < 4; ni++)
                acc[mi][ni] = __builtin_amdgcn_mfma_f32_16x16x32_bf16(af[mi], bfv0[ni], acc[mi][ni], 0, 0, 0);
        __builtin_amdgcn_s_setprio(0);
        __builtin_amdgcn_s_barrier();
        // ---------- P1: words half 1; frags kk0 mi4-7
        if (pf) load_words(t + 1, 1);
        ldsA(0, 1, af);
        __builtin_amdgcn_s_barrier();
        asm volatile("s_waitcnt lgkmcnt(0)" ::: "memory");
        __builtin_amdgcn_sched_barrier(0);
        __builtin_amdgcn_s_setprio(1);
#pragma unroll
        for (int mi = 0; mi < 4; mi++)
#pragma unroll
            for (int ni = 0; ni < 4; ni++)
                acc[4+mi][ni] = __builtin_amdgcn_mfma_f32_16x16x32_bf16(af[mi], bfv0[ni], acc[4+mi][ni], 0, 0, 0);
        __builtin_amdgcn_s_setprio(0);
        __builtin_amdgcn_s_barrier();
        // ---------- P2: frags kk1 mi0-3
        ldsB(1, bfv1); ldsA(1, 0, af);
        __builtin_amdgcn_s_barrier();
        asm volatile("s_waitcnt lgkmcnt(0)" ::: "memory");
        __builtin_amdgcn_sched_barrier(0);
        __builtin_amdgcn_s_setprio(1);
#pragma unroll
        for (int mi = 0; mi < 4; mi++)
#pragma unroll
            for (int ni = 0; ni < 4; ni++)
                acc[mi][ni] = __builtin_amdgcn_mfma_f32_16x16x32_bf16(af[mi], bfv1[ni], acc[mi][ni], 0, 0, 0);
        __builtin_amdgcn_s_setprio(0);
        __builtin_amdgcn_s_barrier();
        // ---------- P3: drain staging (3 phases of flight), dequant -> Bs[nxt]
        asm volatile("s_waitcnt vmcnt(0)" ::: "memory");
        __builtin_amdgcn_sched_barrier(0);
        if (pf) dequant(cur ^ 1);
        ldsA(1, 1, af);
        __builtin_amdgcn_s_barrier();
        asm volatile("s_waitcnt lgkmcnt(0)" ::: "memory");
        __builtin_amdgcn_sched_barrier(0);
        __builtin_amdgcn_s_setprio(1);
#pragma unroll
        for (int mi = 0; mi < 4; mi++)
#pragma unroll
            for (int ni = 0; ni < 4; ni++)
                acc[4+mi][ni] = __builtin_amdgcn_mfma_f32_16x16x32_bf16(af[mi], bfv1[ni], acc[4+mi][ni], 0, 0, 0);
        __builtin_amdgcn_s_setprio(0);
        __builtin_amdgcn_s_barrier();
        cur ^= 1;
    }

    // epilogue: C/D layout col=lane&15, row=(lane>>4)*4+reg
    const int rbase = m0 + (wm << 7) + ((lane >> 4) << 2);
    const int cbase = n0 + (wn << 6) + (lane & 15);
#pragma unroll
    for (int mi = 0; mi < 8; mi++) {
#pragma unroll
        for (int r = 0; r < 4; r++) {
            int row = rbase + (mi << 4) + r;
#pragma unroll
            for (int ni = 0; ni < 4; ni++) {
                int col = cbase + (ni << 4);
                float v = acc[mi][ni][r];
                if (MODE == 2) {
                    ((unsigned short*)out0)[(size_t)z * ((size_t)1024 * N) + (size_t)row * N + col] = f2bf(v);
                } else {
                    ((unsigned short*)outp)[(size_t)row * N + col] = f2bf(v);
                }
            }
        }
    }
}

// ---------------------------------------------------------------------------
// Split-K reduce: out = base + sum of 4 bf16 partials (each 1024x4096)
// ---------------------------------------------------------------------------
__global__ __launch_bounds__(256)
void reduce4_kernel(const float* __restrict__ base, const unsigned short* __restrict__ part,
                    float* __restrict__ out)
{
    const size_t i = (size_t)blockIdx.x * 256 + threadIdx.x;   // 8 elems/thread
    const size_t stride = (size_t)1024 * 4096;
    float s[8];
    float4 a0 = ((const float4*)base)[2*i], a1 = ((const float4*)base)[2*i+1];
    s[0]=a0.x; s[1]=a0.y; s[2]=a0.z; s[3]=a0.w; s[4]=a1.x; s[5]=a1.y; s[6]=a1.z; s[7]=a1.w;
#pragma unroll
    for (int p = 0; p < 4; p++) {
        uint4v v = *(const uint4v*)(part + p * stride + i * 8);
#pragma unroll
        for (int j = 0; j < 4; j++) {
            s[2*j]   += bf2f((unsigned short)(v[j] & 0xFFFF));
            s[2*j+1] += bf2f((unsigned short)(v[j] >> 16));
        }
    }
    float4 o0 = {s[0],s[1],s[2],s[3]}, o1 = {s[4],s[5],s[6],s[7]};
    ((float4*)out)[2*i] = o0; ((float4*)out)[2*i+1] = o1;
}

// ---------------------------------------------------------------------------
// RoPE + layout glue
// ---------------------------------------------------------------------------
__global__ __launch_bounds__(256)
void rope_kernel(const int* __restrict__ positions, const unsigned short* __restrict__ qkv,
                 unsigned short* __restrict__ Qr, unsigned short* __restrict__ Kr,
                 unsigned short* __restrict__ Vtp)
{
    const int t = blockIdx.x, tid = threadIdx.x;
    const float p = (float)positions[t];
    const unsigned short* row = qkv + (size_t)t * 12288;
#pragma unroll 4
    for (int it = 0; it < 16; it++) {
        int task = (it << 8) + tid;
        int i   = task & 63;
        int hh  = (task >> 6) & 31;
        int isK = task >> 11;
        float fr = p * __expf(-(float)i * 0.14391156831f);
        float s, c;
        __sincosf(fr, &s, &c);
        const unsigned short* src = row + (isK << 12) + (hh << 7);
        float x1 = bf2f(src[i]);
        float x2 = bf2f(src[64 + i]);
        float o1 = x1 * c - x2 * s;
        float o2 = x2 * c + x1 * s;
        if (!isK) { o1 *= 0.08838834764831845f; o2 *= 0.08838834764831845f; }
        unsigned short* dst = (isK ? Kr : Qr) + ((size_t)hh * 1024 + t) * 128;
        dst[i]      = f2bf(o1);
        dst[64 + i] = f2bf(o2);
    }
#pragma unroll 4
    for (int it = 0; it < 16; it++) {
        int task = (it << 8) + tid;
        int d = task & 127, hh = task >> 7;
        Vtp[((size_t)hh * 128 + d) * 1024 + t] = row[8192 + task];
    }
}

// ---------------------------------------------------------------------------
// Flash attention (causal). Block = (qt, head). 4 waves x 16 q-rows.
// ---------------------------------------------------------------------------
__global__ __launch_bounds__(256, 2)
void attn_kernel(const unsigned short* __restrict__ Qr, const unsigned short* __restrict__ Kr,
                 const unsigned short* __restrict__ Vtp, unsigned short* __restrict__ attn_out)
{
    __shared__ unsigned short Ks[64 * 128];
    __shared__ unsigned short Vs[128 * 64];
    __shared__ unsigned short Ps[4][16 * 64];
    const int tid = threadIdx.x, lane = tid & 63, w = tid >> 6;
    const int qt = blockIdx.x, h = blockIdx.y;

    const unsigned short* Qh = Qr + ((size_t)h * 1024 + (size_t)qt * 64) * 128;

    bf16x8 qf[4];
#pragma unroll
    for (int kk = 0; kk < 4; kk++)
        qf[kk] = *(const bf16x8*)(Qh + (size_t)((w << 4) + (lane & 15)) * 128 + (kk << 5) + ((lane >> 4) << 3));

    f32x4 o[8];
#pragma unroll
    for (int i = 0; i < 8; i++) { f32x4 zf = {0.f,0.f,0.f,0.f}; o[i] = zf; }
    float Mr[4] = {-1e30f, -1e30f, -1e30f, -1e30f};
    float Lr[4] = {0.f, 0.f, 0.f, 0.f};
    const int qrow0 = (qt << 6) + (w << 4) + ((lane >> 4) << 2);

    for (int kt = 0; kt <= qt; kt++) {
        __syncthreads();
#pragma unroll
        for (int j = 0; j < 4; j++) {
            int slot = (j << 8) + tid;
            int rw = slot >> 4, s = slot & 15;
            int ssrc = (s & 8) | ((s ^ (rw & 7)) & 7);
            const uint4v* src = (const uint4v*)(Kr + ((size_t)h * 1024 + (size_t)kt * 64 + rw) * 128 + (ssrc << 3));
            *(uint4v*)(&Ks[(rw << 7) + (s << 3)]) = *src;
        }
#pragma unroll
        for (int j = 0; j < 4; j++) {
            int slot = (j << 8) + tid;
            int rw = slot >> 3, s = slot & 7;
            const uint4v* src = (const uint4v*)(Vtp + ((size_t)h * 128 + rw) * 1024 + (kt << 6) + ((s ^ (rw & 7)) << 3));
            *(uint4v*)(&Vs[(rw << 6) + (s << 3)]) = *src;
        }
        __syncthreads();

        f32x4 sc4[4];
#pragma unroll
        for (int ni = 0; ni < 4; ni++) { f32x4 zf = {0.f,0.f,0.f,0.f}; sc4[ni] = zf; }
#pragma unroll
        for (int kk = 0; kk < 4; kk++) {
#pragma unroll
            for (int ni = 0; ni < 4; ni++) {
                int r = (ni << 4) + (lane & 15);
                int s = (kk << 2) + (lane >> 4);
                int sp = (s & 8) | ((s ^ (r & 7)) & 7);
                bf16x8 kf = *(const bf16x8*)(&Ks[(r << 7) + (sp << 3)]);
                sc4[ni] = __builtin_amdgcn_mfma_f32_16x16x32_bf16(qf[kk], kf, sc4[ni], 0, 0, 0);
            }
        }

#pragma unroll
        for (int r = 0; r < 4; r++) {
            int qg = qrow0 + r;
            float mx = -1e30f;
#pragma unroll
            for (int ni = 0; ni < 4; ni++) {
                int kg_ = (kt << 6) + (ni << 4) + (lane & 15);
                float v = sc4[ni][r];
                if (kt == qt && kg_ > qg) { v = -1e30f; sc4[ni][r] = v; }
                mx = fmaxf(mx, v);
            }
#pragma unroll
            for (int m_ = 1; m_ < 16; m_ <<= 1) mx = fmaxf(mx, __shfl_xor(mx, m_));
            float mnew  = fmaxf(Mr[r], mx);
            float alpha = __expf(Mr[r] - mnew);
            Mr[r] = mnew;
            float rs = 0.f;
#pragma unroll
            for (int ni = 0; ni < 4; ni++) {
                float pv = __expf(sc4[ni][r] - mnew);
                sc4[ni][r] = pv;
                rs += pv;
            }
#pragma unroll
            for (int m_ = 1; m_ < 16; m_ <<= 1) rs += __shfl_xor(rs, m_);
            Lr[r] = Lr[r] * alpha + rs;
#pragma unroll
            for (int nd = 0; nd < 8; nd++) o[nd][r] *= alpha;
        }

#pragma unroll
        for (int r = 0; r < 4; r++) {
            int qr = ((lane >> 4) << 2) + r;
#pragma unroll
            for (int ni = 0; ni < 4; ni++) {
                int col = (ni << 4) + (lane & 15);
                int phys = (col >> 3) ^ (qr & 7);
                Ps[w][(qr << 6) + (phys << 3) + (col & 7)] = f2bf(sc4[ni][r]);
            }
        }
#pragma unroll
        for (int kk2 = 0; kk2 < 2; kk2++) {
            int rowp = lane & 15;
            int sl = (kk2 << 2) + (lane >> 4);
            bf16x8 pa = *(const bf16x8*)(&Ps[w][(rowp << 6) + ((sl ^ (rowp & 7)) << 3)]);
#pragma unroll
            for (int nd = 0; nd < 8; nd++) {
                int rv = (nd << 4) + (lane & 15);
                bf16x8 vb = *(const bf16x8*)(&Vs[(rv << 6) + ((sl ^ (rv & 7)) << 3)]);
                o[nd] = __builtin_amdgcn_mfma_f32_16x16x32_bf16(pa, vb, o[nd], 0, 0, 0);
            }
        }
    }

#pragma unroll
    for (int r = 0; r < 4; r++) {
        float inv = 1.0f / Lr[r];
        int trow = qrow0 + r;
#pragma unroll
        for (int nd = 0; nd < 8; nd++) {
            int col = (h << 7) + (nd << 4) + (lane & 15);
            attn_out[(size_t)trow * 4096 + col] = f2bf(o[nd][r] * inv);
        }
    }
}

// ---------------------------------------------------------------------------
// silu(gate) * up, bf16, in-place into `up` (recomputed each call)
// ---------------------------------------------------------------------------
__global__ __launch_bounds__(256)
void silu_mul_kernel(const unsigned short* __restrict__ gate, unsigned short* __restrict__ up)
{
    size_t idx = ((size_t)blockIdx.x * 256 + threadIdx.x) * 8;
    uint4v g = *(const uint4v*)(gate + idx);
    uint4v u = *(const uint4v*)(up + idx);
    unsigned int outp[4];
#pragma unroll
    for (int j = 0; j < 4; j++) {
        unsigned int gw = g[j], uw = u[j];
        float g0 = bf2f((unsigned short)(gw & 0xFFFF)), g1 = bf2f((unsigned short)(gw >> 16));
        float u0 = bf2f((unsigned short)(uw & 0xFFFF)), u1 = bf2f((unsigned short)(uw >> 16));
        float s0 = g0 / (1.f + __expf(-g0)) * u0;
        float s1 = g1 / (1.f + __expf(-g1)) * u1;
        outp[j] = (unsigned int)f2bf(s0) | ((unsigned int)f2bf(s1) << 16);
    }
    uint4v ov = {outp[0], outp[1], outp[2], outp[3]};
    *(uint4v*)(up + idx) = ov;
}

// ---------------------------------------------------------------------------
// Launcher
// ---------------------------------------------------------------------------
extern "C" void kernel_launch(void* const* d_in, const int* in_sizes, int n_in,
                              void* d_out, int out_size, void* d_ws, size_t ws_size,
                              hipStream_t stream)
{
    const int*   positions = (const int*)  d_in[0];
    const float* hidden    = (const float*)d_in[1];
    const float* ln1       = (const float*)d_in[2];
    const float* ln2       = (const float*)d_in[3];
    const int*   qkv_qw    = (const int*)  d_in[4];
    const int*   qkv_qz    = (const int*)  d_in[5];
    const float* qkv_sc    = (const float*)d_in[6];
    const int*   o_qw      = (const int*)  d_in[7];
    const int*   o_qz      = (const int*)  d_in[8];
    const float* o_sc      = (const float*)d_in[9];
    const int*   gate_qw   = (const int*)  d_in[10];
    const int*   gate_qz   = (const int*)  d_in[11];
    const float* gate_sc   = (const float*)d_in[12];
    const int*   up_qw     = (const int*)  d_in[13];
    const int*   up_qz     = (const int*)  d_in[14];
    const float* up_sc     = (const float*)d_in[15];
    const int*   down_qw   = (const int*)  d_in[16];
    const int*   down_qz   = (const int*)  d_in[17];
    const float* down_sc   = (const float*)d_in[18];

    char* ws = (char*)d_ws;
    // attention phase layout
    unsigned short* xln   = (unsigned short*)(ws + 0);          //  8.39 MB
    unsigned short* qkvb  = (unsigned short*)(ws + 8388608);    // 25.17 MB
    unsigned short* Qrp   = (unsigned short*)(ws + 33554432);   //  8.39 MB
    unsigned short* Krp   = (unsigned short*)(ws + 41943040);   //  8.39 MB
    unsigned short* Vtp   = (unsigned short*)(ws + 50331648);   //  8.39 MB
    float*          hid   = (float*)        (ws + 67108864);    // 16.78 MB [67.1..83.9)
    unsigned short* attnb = (unsigned short*)(ws + 87961600);   //  8.39 MB [83.9+4MB pad..]
    unsigned short* part  = (unsigned short*)(ws + 0);          // 4 x 8.39 MB partials [0..33.6)
    // MLP phase
    unsigned short* x2    = (unsigned short*)(ws + 0);          //  8.39 MB (reuse)
    unsigned short* gateb = (unsigned short*)(ws + 8388608);    // 22.54 MB [8.39..30.9)
    unsigned short* upb   = (unsigned short*)(ws + 33554432);   // 22.54 MB [33.6..56.1)

    // --- attention block ---
    rmsnorm_kernel<<<1024, 256, 0, stream>>>(hidden, ln1, xln);
    awq_gemm<0><<<dim3(48, 4), 512, 0, stream>>>(xln, qkv_qw, qkv_qz, qkv_sc,
                                                 nullptr, nullptr, nullptr,
                                                 (void*)qkvb, nullptr, 12288, 4096, 0);
    rope_kernel<<<1024, 256, 0, stream>>>(positions, qkvb, Qrp, Krp, Vtp);
    attn_kernel<<<dim3(16, 32), 256, 0, stream>>>(Qrp, Krp, Vtp, attnb);
    // o-proj: split-K=4, bf16 partials at ws[0..33.6MB) (xln/qkvb/Q/K/V dead)
    awq_gemm<2><<<dim3(16, 4, 4), 512, 0, stream>>>(attnb, o_qw, o_qz, o_sc,
                                                    nullptr, nullptr, nullptr,
                                                    (void*)part, nullptr, 4096, 4096, 1024);
    reduce4_kernel<<<2048, 256, 0, stream>>>(hidden, part, hid);
    // --- MLP block ---
    rmsnorm_kernel<<<1024, 256, 0, stream>>>(hid, ln2, x2);
    awq_gemm<1><<<dim3(43, 4, 2), 512, 0, stream>>>(x2, gate_qw, gate_qz, gate_sc,
                                                    up_qw, up_qz, up_sc,
                                                    (void*)gateb, (void*)upb, 11008, 4096, 0);
    silu_mul_kernel<<<5504, 256, 0, stream>>>(gateb, upb);
    // down: split-K=4 (ksplit=2752), partials at ws[0..33.6) (x2/gateb dead)
    awq_gemm<2><<<dim3(16, 4, 4), 512, 0, stream>>>(upb, down_qw, down_qz, down_sc,
                                                    nullptr, nullptr, nullptr,
                                                    (void*)part, nullptr, 4096, 11008, 2752);
    reduce4_kernel<<<2048, 256, 0, stream>>>(hid, part, (float*)d_out);
}

// Round 7
// 823.279 us; speedup vs baseline: 1.0872x; 1.0279x over previous
//
#include <hip/hip_runtime.h>
#include <cstdint>

// ---------------------------------------------------------------------------
// Types & helpers
// ---------------------------------------------------------------------------
typedef __attribute__((ext_vector_type(8))) short  bf16x8;   // 8 bf16 = 4 VGPR
typedef __attribute__((ext_vector_type(4))) float  f32x4;
typedef __attribute__((ext_vector_type(4))) unsigned int uint4v;
typedef __attribute__((ext_vector_type(2))) unsigned int uint2v;

typedef const __attribute__((address_space(1))) void* gas_t;
typedef __attribute__((address_space(3))) void* las_t;

__device__ __forceinline__ float bf2f(unsigned short b) {
    union { unsigned int u; float f; } v; v.u = ((unsigned int)b) << 16; return v.f;
}
__device__ __forceinline__ unsigned short f2bf(float f) {
    union { float f; unsigned int u; } v; v.f = f;
    unsigned int r = v.u + 0x7FFFu + ((v.u >> 16) & 1u);   // RNE
    return (unsigned short)(r >> 16);
}
__device__ __forceinline__ float u2f(unsigned int u) {
    union { unsigned int u; float f; } v; v.u = u; return v.f;
}

// ---------------------------------------------------------------------------
// Weight dequant + transpose:  packed qw[K][N/8] int4  ->  Wt[N][K] bf16
// Block 256 thr, tile 64k x 256n (32 packed words wide). Register transpose:
// thread owns an 8k x 8n micro-tile (8 words, same word-col, 8 k-rows),
// writes 8x bf16x8 (16B) at Wt[n][k0..k0+7] -> 128B-coalesced across lanes.
// ---------------------------------------------------------------------------
__global__ __launch_bounds__(256)
void dequant_kernel(const int* __restrict__ qw, const int* __restrict__ qz,
                    const float* __restrict__ sc, unsigned short* __restrict__ out,
                    int NW, int K)
{
    const int t   = threadIdx.x;
    const int wcb = blockIdx.x << 5;
    const int kb  = blockIdx.y << 6;
    const int g   = blockIdx.y >> 1;          // AWQ group (G=128, kb 64-aligned)
    const int N   = NW << 3;
    const int wc  = wcb + (t >> 3);
    const int k0  = kb + ((t & 7) << 3);

    unsigned int w[8];
#pragma unroll
    for (int j = 0; j < 8; j++) w[j] = (unsigned int)qw[(size_t)(k0 + j) * NW + wc];
    const unsigned int zw = (unsigned int)qz[(size_t)g * NW + wc];
    float scv[8];
#pragma unroll
    for (int j2 = 0; j2 < 8; j2++) scv[j2] = sc[(size_t)g * N + (wc << 3) + j2];

#pragma unroll
    for (int j2 = 0; j2 < 8; j2++) {
        const int sh = j2 << 2;
        const float s = scv[j2];
        const float moff = -(8388608.0f + (float)((zw >> sh) & 0xFu)) * s;
        unsigned int pk[4];
#pragma unroll
        for (int i = 0; i < 4; i++) {
            float f0 = fmaf(u2f(((w[2*i]   >> sh) & 0xFu) | 0x4B000000u), s, moff);
            float f1 = fmaf(u2f(((w[2*i+1] >> sh) & 0xFu) | 0x4B000000u), s, moff);
            asm("v_cvt_pk_bf16_f32 %0, %1, %2" : "=v"(pk[i]) : "v"(f0), "v"(f1));
        }
        uint4v ov = {pk[0], pk[1], pk[2], pk[3]};
        *(uint4v*)(out + (size_t)((wc << 3) + j2) * K + k0) = ov;
    }
}

// ---------------------------------------------------------------------------
// RMSNorm: fp32 [T,4096] -> bf16 [T,4096]
// ---------------------------------------------------------------------------
__global__ __launch_bounds__(256)
void rmsnorm_kernel(const float* __restrict__ x, const float* __restrict__ wgt,
                    unsigned short* __restrict__ out)
{
    const int t = blockIdx.x, tid = threadIdx.x;
    const float4* xr = (const float4*)(x + (size_t)t * 4096);
    float4 v[4];
    float ss = 0.f;
#pragma unroll
    for (int j = 0; j < 4; j++) {
        v[j] = xr[(j << 8) + tid];
        ss += v[j].x*v[j].x + v[j].y*v[j].y + v[j].z*v[j].z + v[j].w*v[j].w;
    }
#pragma unroll
    for (int m = 1; m < 64; m <<= 1) ss += __shfl_xor(ss, m);
    __shared__ float red[4];
    if ((tid & 63) == 0) red[tid >> 6] = ss;
    __syncthreads();
    float tot = red[0] + red[1] + red[2] + red[3];
    float rs = rsqrtf(tot * (1.f / 4096.f) + 1e-6f);
    const float4* wr = (const float4*)wgt;
#pragma unroll
    for (int j = 0; j < 4; j++) {
        float4 wv = wr[(j << 8) + tid];
        float4 xv = v[j];
        unsigned int p0 = (unsigned int)f2bf(xv.x*rs*wv.x) | ((unsigned int)f2bf(xv.y*rs*wv.y) << 16);
        unsigned int p1 = (unsigned int)f2bf(xv.z*rs*wv.z) | ((unsigned int)f2bf(xv.w*rs*wv.w) << 16);
        uint2v pk = {p0, p1};
        *(uint2v*)(&out[(size_t)t*4096 + (size_t)(((j << 8) + tid) << 2)]) = pk;
    }
}

// ---------------------------------------------------------------------------
// Pure bf16 B^T GEMM: C[1024,N] = A[1024,K] @ Bt[N,K]^T
// Tile 256x256, BK=64, 512 thr = 8 waves (2M x 4N), wave-tile 128x64.
// LDS 128KB: As/Bs dbuf 2x32KB each, XOR-swizzled 16B slots, staged via
// global_load_lds(16B) with pre-swizzled source.
// 4 phases/K-step, 2 barriers each, lgkmcnt-only waits; single vmcnt(0)
// after P3's MFMA (staging issued at P0 -> full-iteration flight).
// Block mapping: gridDim.x=8 -> n_idx = x + 8*(y>>2), m = y&3: the 4 M-blocks
// sharing a Bt panel land on one XCD (L2 reuse).
// MODE 0: bf16 out. MODE 1: dual B/out (z). MODE 2: split-K bf16 partials.
// ---------------------------------------------------------------------------
template<int MODE>
__global__ __launch_bounds__(512, 2)
void bt_gemm(const unsigned short* __restrict__ A,
             const unsigned short* __restrict__ Bt0,
             const unsigned short* __restrict__ Bt1,
             void* __restrict__ out0, void* __restrict__ out1,
             int N, int K, int NB, int ksplit)
{
    const int n_idx = blockIdx.x + ((blockIdx.y >> 2) << 3);
    if (n_idx >= NB) return;

    __shared__ unsigned short As[2][256 * 64];
    __shared__ unsigned short Bs[2][256 * 64];

    const int tid  = threadIdx.x;
    const int lane = tid & 63;
    const int wid  = tid >> 6;
    const int wm   = wid >> 2, wn = wid & 3;
    const int m0   = (blockIdx.y & 3) << 8;
    const int n0   = n_idx << 8;
    const int z    = blockIdx.z;

    const unsigned short* Bt = Bt0;
    void* outp = out0;
    if (MODE == 1 && z == 1) { Bt = Bt1; outp = out1; }
    const int k0base = (MODE == 2) ? z * ksplit : 0;
    const int nsteps = ((MODE == 2) ? ksplit : K) >> 6;

    f32x4 acc[8][4];
#pragma unroll
    for (int i = 0; i < 8; i++)
#pragma unroll
        for (int j = 0; j < 4; j++) { f32x4 zv = {0.f,0.f,0.f,0.f}; acc[i][j] = zv; }

    int cur = 0;

    auto stage = [&](int t, int buf) {
        const int k0 = k0base + (t << 6);
#pragma unroll
        for (int i = 0; i < 4; i++) {
            int slot = (i << 9) + tid;
            int row = slot >> 3, s = slot & 7;
            __builtin_amdgcn_global_load_lds(
                (gas_t)(A + (size_t)(m0 + row) * K + k0 + ((s ^ (row & 7)) << 3)),
                (las_t)&As[buf][((i << 9) + (wid << 6)) << 3], 16, 0, 0);
        }
#pragma unroll
        for (int i = 0; i < 4; i++) {
            int slot = (i << 9) + tid;
            int row = slot >> 3, s = slot & 7;
            __builtin_amdgcn_global_load_lds(
                (gas_t)(Bt + (size_t)(n0 + row) * K + k0 + ((s ^ (row & 7)) << 3)),
                (las_t)&Bs[buf][((i << 9) + (wid << 6)) << 3], 16, 0, 0);
        }
    };
    auto ldsA = [&](int kk, int mh, bf16x8* af) {
        const int srow = (kk << 2) + (lane >> 4);
#pragma unroll
        for (int mi = 0; mi < 4; mi++) {
            int r = (wm << 7) + (((mh << 2) + mi) << 4) + (lane & 15);
            af[mi] = *(const bf16x8*)(&As[cur][(r << 6) + ((srow ^ (r & 7)) << 3)]);
        }
    };
    auto ldsB = [&](int kk, bf16x8* bfv) {
        const int srow = (kk << 2) + (lane >> 4);
#pragma unroll
        for (int ni = 0; ni < 4; ni++) {
            int r = (wn << 6) + (ni << 4) + (lane & 15);
            bfv[ni] = *(const bf16x8*)(&Bs[cur][(r << 6) + ((srow ^ (r & 7)) << 3)]);
        }
    };

    stage(0, 0);
    asm volatile("s_waitcnt vmcnt(0)" ::: "memory");
    __builtin_amdgcn_s_barrier();
    __builtin_amdgcn_sched_barrier(0);

    for (int t = 0; t < nsteps; t++) {
        const bool pf = (t + 1 < nsteps);
        bf16x8 af[4], bfv0[4], bfv1[4];
        // ---------- P0: issue staging for t+1; frags kk0, mi0-3
        if (pf) stage(t + 1, cur ^ 1);
        ldsB(0, bfv0); ldsA(0, 0, af);
        __builtin_amdgcn_s_barrier();
        asm volatile("s_waitcnt lgkmcnt(0)" ::: "memory");
        __builtin_amdgcn_sched_barrier(0);
        __builtin_amdgcn_s_setprio(1);
#pragma unroll
        for (int mi = 0; mi < 4; mi++)
#pragma unroll
            for (int ni = 0; ni < 4; ni++)
                acc[mi][ni] = __builtin_amdgcn_mfma_f32_16x16x32_bf16(af[mi], bfv0[ni], acc[mi][ni], 0, 0, 0);
        __builtin_amdgcn_s_setprio(0);
        __builtin_amdgcn_s_barrier();
        // ---------- P1: frags kk0, mi4-7
        ldsA(0, 1, af);
        __builtin_amdgcn_s_barrier();
        asm volatile("s_waitcnt lgkmcnt(0)" ::: "memory");
        __builtin_amdgcn_sched_barrier(0);
        __builtin_amdgcn_s_setprio(1);
#pragma unroll
        for (int mi = 0; mi < 4; mi++)
#pragma unroll
            for (int ni = 0; ni < 4; ni++)
                acc[4+mi][ni] = __builtin_amdgcn_mfma_f32_16x16x32_bf16(af[mi], bfv0[ni], acc[4+mi][ni], 0, 0, 0);
        __builtin_amdgcn_s_setprio(0);
        __builtin_amdgcn_s_barrier();
        // ---------- P2: frags kk1, mi0-3
        ldsB(1, bfv1); ldsA(1, 0, af);
        __builtin_amdgcn_s_barrier();
        asm volatile("s_waitcnt lgkmcnt(0)" ::: "memory");
        __builtin_amdgcn_sched_barrier(0);
        __builtin_amdgcn_s_setprio(1);
#pragma unroll
        for (int mi = 0; mi < 4; mi++)
#pragma unroll
            for (int ni = 0; ni < 4; ni++)
                acc[mi][ni] = __builtin_amdgcn_mfma_f32_16x16x32_bf16(af[mi], bfv1[ni], acc[mi][ni], 0, 0, 0);
        __builtin_amdgcn_s_setprio(0);
        __builtin_amdgcn_s_barrier();
        // ---------- P3: frags kk1, mi4-7; drain staging at the very end
        ldsA(1, 1, af);
        __builtin_amdgcn_s_barrier();
        asm volatile("s_waitcnt lgkmcnt(0)" ::: "memory");
        __builtin_amdgcn_sched_barrier(0);
        __builtin_amdgcn_s_setprio(1);
#pragma unroll
        for (int mi = 0; mi < 4; mi++)
#pragma unroll
            for (int ni = 0; ni < 4; ni++)
                acc[4+mi][ni] = __builtin_amdgcn_mfma_f32_16x16x32_bf16(af[mi], bfv1[ni], acc[4+mi][ni], 0, 0, 0);
        __builtin_amdgcn_s_setprio(0);
        asm volatile("s_waitcnt vmcnt(0)" ::: "memory");   // t+1 tiles landed
        __builtin_amdgcn_s_barrier();
        __builtin_amdgcn_sched_barrier(0);
        cur ^= 1;
    }

    // epilogue: C/D layout col=lane&15, row=(lane>>4)*4+reg
    const int rbase = m0 + (wm << 7) + ((lane >> 4) << 2);
    const int cbase = n0 + (wn << 6) + (lane & 15);
#pragma unroll
    for (int mi = 0; mi < 8; mi++) {
#pragma unroll
        for (int r = 0; r < 4; r++) {
            int row = rbase + (mi << 4) + r;
#pragma unroll
            for (int ni = 0; ni < 4; ni++) {
                int col = cbase + (ni << 4);
                float v = acc[mi][ni][r];
                if (MODE == 2) {
                    ((unsigned short*)out0)[(size_t)z * ((size_t)1024 * N) + (size_t)row * N + col] = f2bf(v);
                } else {
                    ((unsigned short*)outp)[(size_t)row * N + col] = f2bf(v);
                }
            }
        }
    }
}

// ---------------------------------------------------------------------------
// Split-K reduce: out = base + sum of 4 bf16 partials (each 1024x4096)
// ---------------------------------------------------------------------------
__global__ __launch_bounds__(256)
void reduce4_kernel(const float* __restrict__ base, const unsigned short* __restrict__ part,
                    float* __restrict__ out)
{
    const size_t i = (size_t)blockIdx.x * 256 + threadIdx.x;   // 8 elems/thread
    const size_t stride = (size_t)1024 * 4096;
    float s[8];
    float4 a0 = ((const float4*)base)[2*i], a1 = ((const float4*)base)[2*i+1];
    s[0]=a0.x; s[1]=a0.y; s[2]=a0.z; s[3]=a0.w; s[4]=a1.x; s[5]=a1.y; s[6]=a1.z; s[7]=a1.w;
#pragma unroll
    for (int p = 0; p < 4; p++) {
        uint4v v = *(const uint4v*)(part + p * stride + i * 8);
#pragma unroll
        for (int j = 0; j < 4; j++) {
            s[2*j]   += bf2f((unsigned short)(v[j] & 0xFFFF));
            s[2*j+1] += bf2f((unsigned short)(v[j] >> 16));
        }
    }
    float4 o0 = {s[0],s[1],s[2],s[3]}, o1 = {s[4],s[5],s[6],s[7]};
    ((float4*)out)[2*i] = o0; ((float4*)out)[2*i+1] = o1;
}

// ---------------------------------------------------------------------------
// RoPE + layout glue
// ---------------------------------------------------------------------------
__global__ __launch_bounds__(256)
void rope_kernel(const int* __restrict__ positions, const unsigned short* __restrict__ qkv,
                 unsigned short* __restrict__ Qr, unsigned short* __restrict__ Kr,
                 unsigned short* __restrict__ Vtp)
{
    const int t = blockIdx.x, tid = threadIdx.x;
    const float p = (float)positions[t];
    const unsigned short* row = qkv + (size_t)t * 12288;
#pragma unroll 4
    for (int it = 0; it < 16; it++) {
        int task = (it << 8) + tid;
        int i   = task & 63;
        int hh  = (task >> 6) & 31;
        int isK = task >> 11;
        float fr = p * __expf(-(float)i * 0.14391156831f);
        float s, c;
        __sincosf(fr, &s, &c);
        const unsigned short* src = row + (isK << 12) + (hh << 7);
        float x1 = bf2f(src[i]);
        float x2 = bf2f(src[64 + i]);
        float o1 = x1 * c - x2 * s;
        float o2 = x2 * c + x1 * s;
        if (!isK) { o1 *= 0.08838834764831845f; o2 *= 0.08838834764831845f; }
        unsigned short* dst = (isK ? Kr : Qr) + ((size_t)hh * 1024 + t) * 128;
        dst[i]      = f2bf(o1);
        dst[64 + i] = f2bf(o2);
    }
#pragma unroll 4
    for (int it = 0; it < 16; it++) {
        int task = (it << 8) + tid;
        int d = task & 127, hh = task >> 7;
        Vtp[((size_t)hh * 128 + d) * 1024 + t] = row[8192 + task];
    }
}

// ---------------------------------------------------------------------------
// Flash attention (causal). Block = (qt, head). 4 waves x 16 q-rows.
// ---------------------------------------------------------------------------
__global__ __launch_bounds__(256, 2)
void attn_kernel(const unsigned short* __restrict__ Qr, const unsigned short* __restrict__ Kr,
                 const unsigned short* __restrict__ Vtp, unsigned short* __restrict__ attn_out)
{
    __shared__ unsigned short Ks[64 * 128];
    __shared__ unsigned short Vs[128 * 64];
    __shared__ unsigned short Ps[4][16 * 64];
    const int tid = threadIdx.x, lane = tid & 63, w = tid >> 6;
    const int qt = blockIdx.x, h = blockIdx.y;

    const unsigned short* Qh = Qr + ((size_t)h * 1024 + (size_t)qt * 64) * 128;

    bf16x8 qf[4];
#pragma unroll
    for (int kk = 0; kk < 4; kk++)
        qf[kk] = *(const bf16x8*)(Qh + (size_t)((w << 4) + (lane & 15)) * 128 + (kk << 5) + ((lane >> 4) << 3));

    f32x4 o[8];
#pragma unroll
    for (int i = 0; i < 8; i++) { f32x4 zf = {0.f,0.f,0.f,0.f}; o[i] = zf; }
    float Mr[4] = {-1e30f, -1e30f, -1e30f, -1e30f};
    float Lr[4] = {0.f, 0.f, 0.f, 0.f};
    const int qrow0 = (qt << 6) + (w << 4) + ((lane >> 4) << 2);

    for (int kt = 0; kt <= qt; kt++) {
        __syncthreads();
#pragma unroll
        for (int j = 0; j < 4; j++) {
            int slot = (j << 8) + tid;
            int rw = slot >> 4, s = slot & 15;
            int ssrc = (s & 8) | ((s ^ (rw & 7)) & 7);
            const uint4v* src = (const uint4v*)(Kr + ((size_t)h * 1024 + (size_t)kt * 64 + rw) * 128 + (ssrc << 3));
            *(uint4v*)(&Ks[(rw << 7) + (s << 3)]) = *src;
        }
#pragma unroll
        for (int j = 0; j < 4; j++) {
            int slot = (j << 8) + tid;
            int rw = slot >> 3, s = slot & 7;
            const uint4v* src = (const uint4v*)(Vtp + ((size_t)h * 128 + rw) * 1024 + (kt << 6) + ((s ^ (rw & 7)) << 3));
            *(uint4v*)(&Vs[(rw << 6) + (s << 3)]) = *src;
        }
        __syncthreads();

        f32x4 sc4[4];
#pragma unroll
        for (int ni = 0; ni < 4; ni++) { f32x4 zf = {0.f,0.f,0.f,0.f}; sc4[ni] = zf; }
#pragma unroll
        for (int kk = 0; kk < 4; kk++) {
#pragma unroll
            for (int ni = 0; ni < 4; ni++) {
                int r = (ni << 4) + (lane & 15);
                int s = (kk << 2) + (lane >> 4);
                int sp = (s & 8) | ((s ^ (r & 7)) & 7);
                bf16x8 kf = *(const bf16x8*)(&Ks[(r << 7) + (sp << 3)]);
                sc4[ni] = __builtin_amdgcn_mfma_f32_16x16x32_bf16(qf[kk], kf, sc4[ni], 0, 0, 0);
            }
        }

#pragma unroll
        for (int r = 0; r < 4; r++) {
            int qg = qrow0 + r;
            float mx = -1e30f;
#pragma unroll
            for (int ni = 0; ni < 4; ni++) {
                int kg_ = (kt << 6) + (ni << 4) + (lane & 15);
                float v = sc4[ni][r];
                if (kt == qt && kg_ > qg) { v = -1e30f; sc4[ni][r] = v; }
                mx = fmaxf(mx, v);
            }
#pragma unroll
            for (int m_ = 1; m_ < 16; m_ <<= 1) mx = fmaxf(mx, __shfl_xor(mx, m_));
            float mnew  = fmaxf(Mr[r], mx);
            float alpha = __expf(Mr[r] - mnew);
            Mr[r] = mnew;
            float rs = 0.f;
#pragma unroll
            for (int ni = 0; ni < 4; ni++) {
                float pv = __expf(sc4[ni][r] - mnew);
                sc4[ni][r] = pv;
                rs += pv;
            }
#pragma unroll
            for (int m_ = 1; m_ < 16; m_ <<= 1) rs += __shfl_xor(rs, m_);
            Lr[r] = Lr[r] * alpha + rs;
#pragma unroll
            for (int nd = 0; nd < 8; nd++) o[nd][r] *= alpha;
        }

#pragma unroll
        for (int r = 0; r < 4; r++) {
            int qr = ((lane >> 4) << 2) + r;
#pragma unroll
            for (int ni = 0; ni < 4; ni++) {
                int col = (ni << 4) + (lane & 15);
                int phys = (col >> 3) ^ (qr & 7);
                Ps[w][(qr << 6) + (phys << 3) + (col & 7)] = f2bf(sc4[ni][r]);
            }
        }
#pragma unroll
        for (int kk2 = 0; kk2 < 2; kk2++) {
            int rowp = lane & 15;
            int sl = (kk2 << 2) + (lane >> 4);
            bf16x8 pa = *(const bf16x8*)(&Ps[w][(rowp << 6) + ((sl ^ (rowp & 7)) << 3)]);
#pragma unroll
            for (int nd = 0; nd < 8; nd++) {
                int rv = (nd << 4) + (lane & 15);
                bf16x8 vb = *(const bf16x8*)(&Vs[(rv << 6) + ((sl ^ (rv & 7)) << 3)]);
                o[nd] = __builtin_amdgcn_mfma_f32_16x16x32_bf16(pa, vb, o[nd], 0, 0, 0);
            }
        }
    }

#pragma unroll
    for (int r = 0; r < 4; r++) {
        float inv = 1.0f / Lr[r];
        int trow = qrow0 + r;
#pragma unroll
        for (int nd = 0; nd < 8; nd++) {
            int col = (h << 7) + (nd << 4) + (lane & 15);
            attn_out[(size_t)trow * 4096 + col] = f2bf(o[nd][r] * inv);
        }
    }
}

// ---------------------------------------------------------------------------
// silu(gate) * up, bf16, in-place into `up` (recomputed each call)
// ---------------------------------------------------------------------------
__global__ __launch_bounds__(256)
void silu_mul_kernel(const unsigned short* __restrict__ gate, unsigned short* __restrict__ up)
{
    size_t idx = ((size_t)blockIdx.x * 256 + threadIdx.x) * 8;
    uint4v g = *(const uint4v*)(gate + idx);
    uint4v u = *(const uint4v*)(up + idx);
    unsigned int outp[4];
#pragma unroll
    for (int j = 0; j < 4; j++) {
        unsigned int gw = g[j], uw = u[j];
        float g0 = bf2f((unsigned short)(gw & 0xFFFF)), g1 = bf2f((unsigned short)(gw >> 16));
        float u0 = bf2f((unsigned short)(uw & 0xFFFF)), u1 = bf2f((unsigned short)(uw >> 16));
        float s0 = g0 / (1.f + __expf(-g0)) * u0;
        float s1 = g1 / (1.f + __expf(-g1)) * u1;
        outp[j] = (unsigned int)f2bf(s0) | ((unsigned int)f2bf(s1) << 16);
    }
    uint4v ov = {outp[0], outp[1], outp[2], outp[3]};
    *(uint4v*)(up + idx) = ov;
}

// ---------------------------------------------------------------------------
// Launcher
// ---------------------------------------------------------------------------
extern "C" void kernel_launch(void* const* d_in, const int* in_sizes, int n_in,
                              void* d_out, int out_size, void* d_ws, size_t ws_size,
                              hipStream_t stream)
{
    const int*   positions = (const int*)  d_in[0];
    const float* hidden    = (const float*)d_in[1];
    const float* ln1       = (const float*)d_in[2];
    const float* ln2       = (const float*)d_in[3];
    const int*   qkv_qw    = (const int*)  d_in[4];
    const int*   qkv_qz    = (const int*)  d_in[5];
    const float* qkv_sc    = (const float*)d_in[6];
    const int*   o_qw      = (const int*)  d_in[7];
    const int*   o_qz      = (const int*)  d_in[8];
    const float* o_sc      = (const float*)d_in[9];
    const int*   gate_qw   = (const int*)  d_in[10];
    const int*   gate_qz   = (const int*)  d_in[11];
    const float* gate_sc   = (const float*)d_in[12];
    const int*   up_qw     = (const int*)  d_in[13];
    const int*   up_qz     = (const int*)  d_in[14];
    const float* up_sc     = (const float*)d_in[15];
    const int*   down_qw   = (const int*)  d_in[16];
    const int*   down_qz   = (const int*)  d_in[17];
    const float* down_sc   = (const float*)d_in[18];

    char* ws = (char*)d_ws;
    const size_t MB = 1 << 20;
    // Wt region 0..172 MiB: qkv 96 / o 32 / gate 86 + up 86 / down 86
    unsigned short* Wt    = (unsigned short*)(ws + 0);
    unsigned short* Wu    = (unsigned short*)(ws + 86 * MB);    // up weights
    unsigned short* parto = (unsigned short*)(ws + 40 * MB);    // 32 MiB (o phase)
    unsigned short* partd = (unsigned short*)(ws + 96 * MB);    // 32 MiB (down phase)
    unsigned short* xln   = (unsigned short*)(ws + 176 * MB);   // 8 MiB
    unsigned short* qkvb  = (unsigned short*)(ws + 184 * MB);   // 24 MiB
    unsigned short* Qrp   = (unsigned short*)(ws + 208 * MB);   // 8 MiB
    unsigned short* Krp   = (unsigned short*)(ws + 216 * MB);   // 8 MiB
    unsigned short* Vtp   = (unsigned short*)(ws + 224 * MB);   // 8 MiB
    unsigned short* attnb = (unsigned short*)(ws + 232 * MB);   // 8 MiB -> peak 240 MiB
    unsigned short* x2    = xln;
    unsigned short* gateb = qkvb;                               // 22 MiB
    unsigned short* upb   = Qrp;                                // 22 MiB (Q/K/V dead)
    float*          hid   = (float*)d_out;                      // residual lives in d_out

    // --- attention block ---
    dequant_kernel<<<dim3(48, 64), 256, 0, stream>>>(qkv_qw, qkv_qz, qkv_sc, Wt, 1536, 4096);
    rmsnorm_kernel<<<1024, 256, 0, stream>>>(hidden, ln1, xln);
    bt_gemm<0><<<dim3(8, 24), 512, 0, stream>>>(xln, Wt, nullptr,
                                                (void*)qkvb, nullptr, 12288, 4096, 48, 0);
    rope_kernel<<<1024, 256, 0, stream>>>(positions, qkvb, Qrp, Krp, Vtp);
    dequant_kernel<<<dim3(16, 64), 256, 0, stream>>>(o_qw, o_qz, o_sc, Wt, 512, 4096);
    attn_kernel<<<dim3(16, 32), 256, 0, stream>>>(Qrp, Krp, Vtp, attnb);
    bt_gemm<2><<<dim3(8, 8, 4), 512, 0, stream>>>(attnb, Wt, nullptr,
                                                  (void*)parto, nullptr, 4096, 4096, 16, 1024);
    reduce4_kernel<<<2048, 256, 0, stream>>>(hidden, parto, hid);
    // --- MLP block ---
    rmsnorm_kernel<<<1024, 256, 0, stream>>>(hid, ln2, x2);
    dequant_kernel<<<dim3(43, 64), 256, 0, stream>>>(gate_qw, gate_qz, gate_sc, Wt, 1376, 4096);
    dequant_kernel<<<dim3(43, 64), 256, 0, stream>>>(up_qw, up_qz, up_sc, Wu, 1376, 4096);
    bt_gemm<1><<<dim3(8, 24, 2), 512, 0, stream>>>(x2, Wt, Wu,
                                                   (void*)gateb, (void*)upb, 11008, 4096, 43, 0);
    silu_mul_kernel<<<5504, 256, 0, stream>>>(gateb, upb);
    dequant_kernel<<<dim3(16, 172), 256, 0, stream>>>(down_qw, down_qz, down_sc, Wt, 512, 11008);
    bt_gemm<2><<<dim3(8, 8, 4), 512, 0, stream>>>(upb, Wt, nullptr,
                                                  (void*)partd, nullptr, 4096, 11008, 16, 2752);
    reduce4_kernel<<<2048, 256, 0, stream>>>(hid, partd, (float*)d_out);
}

// Round 8
// 801.904 us; speedup vs baseline: 1.1161x; 1.0267x over previous
//
#include <hip/hip_runtime.h>
#include <cstdint>

// ---------------------------------------------------------------------------
// Types & helpers
// ---------------------------------------------------------------------------
typedef __attribute__((ext_vector_type(8))) short  bf16x8;   // 8 bf16 = 4 VGPR
typedef __attribute__((ext_vector_type(4))) float  f32x4;
typedef __attribute__((ext_vector_type(4))) unsigned int uint4v;
typedef __attribute__((ext_vector_type(2))) unsigned int uint2v;

typedef const __attribute__((address_space(1))) void* gas_t;
typedef __attribute__((address_space(3))) void* las_t;

__device__ __forceinline__ float bf2f(unsigned short b) {
    union { unsigned int u; float f; } v; v.u = ((unsigned int)b) << 16; return v.f;
}
__device__ __forceinline__ unsigned short f2bf(float f) {
    union { float f; unsigned int u; } v; v.f = f;
    unsigned int r = v.u + 0x7FFFu + ((v.u >> 16) & 1u);   // RNE
    return (unsigned short)(r >> 16);
}
__device__ __forceinline__ float u2f(unsigned int u) {
    union { unsigned int u; float f; } v; v.u = u; return v.f;
}

// ---------------------------------------------------------------------------
// Weight dequant + transpose:  packed qw[K][N/8] int4  ->  Wt[N][K] bf16
// (unchanged from R7 — HBM-bound, correct)
// ---------------------------------------------------------------------------
__global__ __launch_bounds__(256)
void dequant_kernel(const int* __restrict__ qw, const int* __restrict__ qz,
                    const float* __restrict__ sc, unsigned short* __restrict__ out,
                    int NW, int K)
{
    const int t   = threadIdx.x;
    const int wcb = blockIdx.x << 5;
    const int kb  = blockIdx.y << 6;
    const int g   = blockIdx.y >> 1;          // AWQ group (G=128)
    const int N   = NW << 3;
    const int wc  = wcb + (t >> 3);
    const int k0  = kb + ((t & 7) << 3);

    unsigned int w[8];
#pragma unroll
    for (int j = 0; j < 8; j++) w[j] = (unsigned int)qw[(size_t)(k0 + j) * NW + wc];
    const unsigned int zw = (unsigned int)qz[(size_t)g * NW + wc];
    float scv[8];
#pragma unroll
    for (int j2 = 0; j2 < 8; j2++) scv[j2] = sc[(size_t)g * N + (wc << 3) + j2];

#pragma unroll
    for (int j2 = 0; j2 < 8; j2++) {
        const int sh = j2 << 2;
        const float s = scv[j2];
        const float moff = -(8388608.0f + (float)((zw >> sh) & 0xFu)) * s;
        unsigned int pk[4];
#pragma unroll
        for (int i = 0; i < 4; i++) {
            float f0 = fmaf(u2f(((w[2*i]   >> sh) & 0xFu) | 0x4B000000u), s, moff);
            float f1 = fmaf(u2f(((w[2*i+1] >> sh) & 0xFu) | 0x4B000000u), s, moff);
            asm("v_cvt_pk_bf16_f32 %0, %1, %2" : "=v"(pk[i]) : "v"(f0), "v"(f1));
        }
        uint4v ov = {pk[0], pk[1], pk[2], pk[3]};
        *(uint4v*)(out + (size_t)((wc << 3) + j2) * K + k0) = ov;
    }
}

// ---------------------------------------------------------------------------
// RMSNorm: fp32 [T,4096] -> bf16 [T,4096]
// ---------------------------------------------------------------------------
__global__ __launch_bounds__(256)
void rmsnorm_kernel(const float* __restrict__ x, const float* __restrict__ wgt,
                    unsigned short* __restrict__ out)
{
    const int t = blockIdx.x, tid = threadIdx.x;
    const float4* xr = (const float4*)(x + (size_t)t * 4096);
    float4 v[4];
    float ss = 0.f;
#pragma unroll
    for (int j = 0; j < 4; j++) {
        v[j] = xr[(j << 8) + tid];
        ss += v[j].x*v[j].x + v[j].y*v[j].y + v[j].z*v[j].z + v[j].w*v[j].w;
    }
#pragma unroll
    for (int m = 1; m < 64; m <<= 1) ss += __shfl_xor(ss, m);
    __shared__ float red[4];
    if ((tid & 63) == 0) red[tid >> 6] = ss;
    __syncthreads();
    float tot = red[0] + red[1] + red[2] + red[3];
    float rs = rsqrtf(tot * (1.f / 4096.f) + 1e-6f);
    const float4* wr = (const float4*)wgt;
#pragma unroll
    for (int j = 0; j < 4; j++) {
        float4 wv = wr[(j << 8) + tid];
        float4 xv = v[j];
        unsigned int p0 = (unsigned int)f2bf(xv.x*rs*wv.x) | ((unsigned int)f2bf(xv.y*rs*wv.y) << 16);
        unsigned int p1 = (unsigned int)f2bf(xv.z*rs*wv.z) | ((unsigned int)f2bf(xv.w*rs*wv.w) << 16);
        uint2v pk = {p0, p1};
        *(uint2v*)(&out[(size_t)t*4096 + (size_t)(((j << 8) + tid) << 2)]) = pk;
    }
}

// ---------------------------------------------------------------------------
// Pure bf16 B^T GEMM, m97 structure (measured 874-912 TF on gfx950):
// C[1024,N] = A[1024,K] @ Bt[N,K]^T
// Tile 128x128, BK=64, 256 thr = 4 waves (2M x 2N), wave-tile 64x64.
// Single-buffer LDS 32KB (3-4 blocks/CU); per K-step:
//   __syncthreads(); issue 8x global_load_lds (pre-swizzled src, linear LDS);
//   __syncthreads(); ds_read frags (XOR-swizzled) + 32 MFMA/wave.
// Latency hiding comes from 3-4 co-resident blocks (m114), not intra-block
// pipelining — the proven-simple structure.
// MODE 0: bf16 out. MODE 1: dual weight/out (blockIdx.z). MODE 3: f32 +res.
// ---------------------------------------------------------------------------
template<int MODE>
__global__ __launch_bounds__(256, 3)
void bt_gemm(const unsigned short* __restrict__ A,
             const unsigned short* __restrict__ Bt0,
             const unsigned short* __restrict__ Bt1,
             void* __restrict__ out0, void* __restrict__ out1,
             const float* __restrict__ res,
             int N, int K)
{
    __shared__ unsigned short As[128 * 64];   // 16KB
    __shared__ unsigned short Bs[128 * 64];   // 16KB

    const int tid  = threadIdx.x;
    const int lane = tid & 63;
    const int wid  = tid >> 6;
    const int wm   = wid >> 1, wn = wid & 1;
    const int m0   = blockIdx.y << 7;
    const int n0   = blockIdx.x << 7;

    const unsigned short* Bt = Bt0;
    void* outp = out0;
    if (MODE == 1 && blockIdx.z == 1) { Bt = Bt1; outp = out1; }

    f32x4 acc[4][4];
#pragma unroll
    for (int i = 0; i < 4; i++)
#pragma unroll
        for (int j = 0; j < 4; j++) { f32x4 zv = {0.f,0.f,0.f,0.f}; acc[i][j] = zv; }

    const int nsteps = K >> 6;
    for (int t = 0; t < nsteps; t++) {
        const int k0 = t << 6;
        __syncthreads();   // previous tile's reads complete
#pragma unroll
        for (int i = 0; i < 4; i++) {
            int slot = (i << 8) + tid;          // 0..1023
            int row = slot >> 3, s = slot & 7;
            __builtin_amdgcn_global_load_lds(
                (gas_t)(A + (size_t)(m0 + row) * K + k0 + ((s ^ (row & 7)) << 3)),
                (las_t)&As[slot << 3], 16, 0, 0);
        }
#pragma unroll
        for (int i = 0; i < 4; i++) {
            int slot = (i << 8) + tid;
            int row = slot >> 3, s = slot & 7;
            __builtin_amdgcn_global_load_lds(
                (gas_t)(Bt + (size_t)(n0 + row) * K + k0 + ((s ^ (row & 7)) << 3)),
                (las_t)&Bs[slot << 3], 16, 0, 0);
        }
        __syncthreads();   // drains vmcnt: tile resident
#pragma unroll
        for (int kk = 0; kk < 2; kk++) {
            const int srow = (kk << 2) + (lane >> 4);
            bf16x8 af[4], bfv[4];
#pragma unroll
            for (int mi = 0; mi < 4; mi++) {
                int r = (wm << 6) + (mi << 4) + (lane & 15);
                af[mi] = *(const bf16x8*)(&As[(r << 6) + ((srow ^ (r & 7)) << 3)]);
            }
#pragma unroll
            for (int ni = 0; ni < 4; ni++) {
                int r = (wn << 6) + (ni << 4) + (lane & 15);
                bfv[ni] = *(const bf16x8*)(&Bs[(r << 6) + ((srow ^ (r & 7)) << 3)]);
            }
#pragma unroll
            for (int mi = 0; mi < 4; mi++)
#pragma unroll
                for (int ni = 0; ni < 4; ni++)
                    acc[mi][ni] = __builtin_amdgcn_mfma_f32_16x16x32_bf16(af[mi], bfv[ni], acc[mi][ni], 0, 0, 0);
        }
    }

    // epilogue: C/D layout col=lane&15, row=(lane>>4)*4+reg
    const int rbase = m0 + (wm << 6) + ((lane >> 4) << 2);
    const int cbase = n0 + (wn << 6) + (lane & 15);
#pragma unroll
    for (int mi = 0; mi < 4; mi++) {
#pragma unroll
        for (int r = 0; r < 4; r++) {
            int row = rbase + (mi << 4) + r;
#pragma unroll
            for (int ni = 0; ni < 4; ni++) {
                int col = cbase + (ni << 4);
                float v = acc[mi][ni][r];
                if (MODE == 3) {
                    ((float*)out0)[(size_t)row * N + col] = v + res[(size_t)row * N + col];
                } else {
                    ((unsigned short*)outp)[(size_t)row * N + col] = f2bf(v);
                }
            }
        }
    }
}

// ---------------------------------------------------------------------------
// RoPE + layout glue
// ---------------------------------------------------------------------------
__global__ __launch_bounds__(256)
void rope_kernel(const int* __restrict__ positions, const unsigned short* __restrict__ qkv,
                 unsigned short* __restrict__ Qr, unsigned short* __restrict__ Kr,
                 unsigned short* __restrict__ Vtp)
{
    const int t = blockIdx.x, tid = threadIdx.x;
    const float p = (float)positions[t];
    const unsigned short* row = qkv + (size_t)t * 12288;
#pragma unroll 4
    for (int it = 0; it < 16; it++) {
        int task = (it << 8) + tid;
        int i   = task & 63;
        int hh  = (task >> 6) & 31;
        int isK = task >> 11;
        float fr = p * __expf(-(float)i * 0.14391156831f);
        float s, c;
        __sincosf(fr, &s, &c);
        const unsigned short* src = row + (isK << 12) + (hh << 7);
        float x1 = bf2f(src[i]);
        float x2 = bf2f(src[64 + i]);
        float o1 = x1 * c - x2 * s;
        float o2 = x2 * c + x1 * s;
        if (!isK) { o1 *= 0.08838834764831845f; o2 *= 0.08838834764831845f; }
        unsigned short* dst = (isK ? Kr : Qr) + ((size_t)hh * 1024 + t) * 128;
        dst[i]      = f2bf(o1);
        dst[64 + i] = f2bf(o2);
    }
#pragma unroll 4
    for (int it = 0; it < 16; it++) {
        int task = (it << 8) + tid;
        int d = task & 127, hh = task >> 7;
        Vtp[((size_t)hh * 128 + d) * 1024 + t] = row[8192 + task];
    }
}

// ---------------------------------------------------------------------------
// Flash attention (causal). Block = (qt, head). 4 waves x 16 q-rows.
// ---------------------------------------------------------------------------
__global__ __launch_bounds__(256, 2)
void attn_kernel(const unsigned short* __restrict__ Qr, const unsigned short* __restrict__ Kr,
                 const unsigned short* __restrict__ Vtp, unsigned short* __restrict__ attn_out)
{
    __shared__ unsigned short Ks[64 * 128];
    __shared__ unsigned short Vs[128 * 64];
    __shared__ unsigned short Ps[4][16 * 64];
    const int tid = threadIdx.x, lane = tid & 63, w = tid >> 6;
    const int qt = blockIdx.x, h = blockIdx.y;

    const unsigned short* Qh = Qr + ((size_t)h * 1024 + (size_t)qt * 64) * 128;

    bf16x8 qf[4];
#pragma unroll
    for (int kk = 0; kk < 4; kk++)
        qf[kk] = *(const bf16x8*)(Qh + (size_t)((w << 4) + (lane & 15)) * 128 + (kk << 5) + ((lane >> 4) << 3));

    f32x4 o[8];
#pragma unroll
    for (int i = 0; i < 8; i++) { f32x4 zf = {0.f,0.f,0.f,0.f}; o[i] = zf; }
    float Mr[4] = {-1e30f, -1e30f, -1e30f, -1e30f};
    float Lr[4] = {0.f, 0.f, 0.f, 0.f};
    const int qrow0 = (qt << 6) + (w << 4) + ((lane >> 4) << 2);

    for (int kt = 0; kt <= qt; kt++) {
        __syncthreads();
#pragma unroll
        for (int j = 0; j < 4; j++) {
            int slot = (j << 8) + tid;
            int rw = slot >> 4, s = slot & 15;
            int ssrc = (s & 8) | ((s ^ (rw & 7)) & 7);
            const uint4v* src = (const uint4v*)(Kr + ((size_t)h * 1024 + (size_t)kt * 64 + rw) * 128 + (ssrc << 3));
            *(uint4v*)(&Ks[(rw << 7) + (s << 3)]) = *src;
        }
#pragma unroll
        for (int j = 0; j < 4; j++) {
            int slot = (j << 8) + tid;
            int rw = slot >> 3, s = slot & 7;
            const uint4v* src = (const uint4v*)(Vtp + ((size_t)h * 128 + rw) * 1024 + (kt << 6) + ((s ^ (rw & 7)) << 3));
            *(uint4v*)(&Vs[(rw << 6) + (s << 3)]) = *src;
        }
        __syncthreads();

        f32x4 sc4[4];
#pragma unroll
        for (int ni = 0; ni < 4; ni++) { f32x4 zf = {0.f,0.f,0.f,0.f}; sc4[ni] = zf; }
#pragma unroll
        for (int kk = 0; kk < 4; kk++) {
#pragma unroll
            for (int ni = 0; ni < 4; ni++) {
                int r = (ni << 4) + (lane & 15);
                int s = (kk << 2) + (lane >> 4);
                int sp = (s & 8) | ((s ^ (r & 7)) & 7);
                bf16x8 kf = *(const bf16x8*)(&Ks[(r << 7) + (sp << 3)]);
                sc4[ni] = __builtin_amdgcn_mfma_f32_16x16x32_bf16(qf[kk], kf, sc4[ni], 0, 0, 0);
            }
        }

#pragma unroll
        for (int r = 0; r < 4; r++) {
            int qg = qrow0 + r;
            float mx = -1e30f;
#pragma unroll
            for (int ni = 0; ni < 4; ni++) {
                int kg_ = (kt << 6) + (ni << 4) + (lane & 15);
                float v = sc4[ni][r];
                if (kt == qt && kg_ > qg) { v = -1e30f; sc4[ni][r] = v; }
                mx = fmaxf(mx, v);
            }
#pragma unroll
            for (int m_ = 1; m_ < 16; m_ <<= 1) mx = fmaxf(mx, __shfl_xor(mx, m_));
            float mnew  = fmaxf(Mr[r], mx);
            float alpha = __expf(Mr[r] - mnew);
            Mr[r] = mnew;
            float rs = 0.f;
#pragma unroll
            for (int ni = 0; ni < 4; ni++) {
                float pv = __expf(sc4[ni][r] - mnew);
                sc4[ni][r] = pv;
                rs += pv;
            }
#pragma unroll
            for (int m_ = 1; m_ < 16; m_ <<= 1) rs += __shfl_xor(rs, m_);
            Lr[r] = Lr[r] * alpha + rs;
#pragma unroll
            for (int nd = 0; nd < 8; nd++) o[nd][r] *= alpha;
        }

#pragma unroll
        for (int r = 0; r < 4; r++) {
            int qr = ((lane >> 4) << 2) + r;
#pragma unroll
            for (int ni = 0; ni < 4; ni++) {
                int col = (ni << 4) + (lane & 15);
                int phys = (col >> 3) ^ (qr & 7);
                Ps[w][(qr << 6) + (phys << 3) + (col & 7)] = f2bf(sc4[ni][r]);
            }
        }
#pragma unroll
        for (int kk2 = 0; kk2 < 2; kk2++) {
            int rowp = lane & 15;
            int sl = (kk2 << 2) + (lane >> 4);
            bf16x8 pa = *(const bf16x8*)(&Ps[w][(rowp << 6) + ((sl ^ (rowp & 7)) << 3)]);
#pragma unroll
            for (int nd = 0; nd < 8; nd++) {
                int rv = (nd << 4) + (lane & 15);
                bf16x8 vb = *(const bf16x8*)(&Vs[(rv << 6) + ((sl ^ (rv & 7)) << 3)]);
                o[nd] = __builtin_amdgcn_mfma_f32_16x16x32_bf16(pa, vb, o[nd], 0, 0, 0);
            }
        }
    }

#pragma unroll
    for (int r = 0; r < 4; r++) {
        float inv = 1.0f / Lr[r];
        int trow = qrow0 + r;
#pragma unroll
        for (int nd = 0; nd < 8; nd++) {
            int col = (h << 7) + (nd << 4) + (lane & 15);
            attn_out[(size_t)trow * 4096 + col] = f2bf(o[nd][r] * inv);
        }
    }
}

// ---------------------------------------------------------------------------
// silu(gate) * up, bf16, in-place into `up` (recomputed each call)
// ---------------------------------------------------------------------------
__global__ __launch_bounds__(256)
void silu_mul_kernel(const unsigned short* __restrict__ gate, unsigned short* __restrict__ up)
{
    size_t idx = ((size_t)blockIdx.x * 256 + threadIdx.x) * 8;
    uint4v g = *(const uint4v*)(gate + idx);
    uint4v u = *(const uint4v*)(up + idx);
    unsigned int outp[4];
#pragma unroll
    for (int j = 0; j < 4; j++) {
        unsigned int gw = g[j], uw = u[j];
        float g0 = bf2f((unsigned short)(gw & 0xFFFF)), g1 = bf2f((unsigned short)(gw >> 16));
        float u0 = bf2f((unsigned short)(uw & 0xFFFF)), u1 = bf2f((unsigned short)(uw >> 16));
        float s0 = g0 / (1.f + __expf(-g0)) * u0;
        float s1 = g1 / (1.f + __expf(-g1)) * u1;
        outp[j] = (unsigned int)f2bf(s0) | ((unsigned int)f2bf(s1) << 16);
    }
    uint4v ov = {outp[0], outp[1], outp[2], outp[3]};
    *(uint4v*)(up + idx) = ov;
}

// ---------------------------------------------------------------------------
// Launcher
// ---------------------------------------------------------------------------
extern "C" void kernel_launch(void* const* d_in, const int* in_sizes, int n_in,
                              void* d_out, int out_size, void* d_ws, size_t ws_size,
                              hipStream_t stream)
{
    const int*   positions = (const int*)  d_in[0];
    const float* hidden    = (const float*)d_in[1];
    const float* ln1       = (const float*)d_in[2];
    const float* ln2       = (const float*)d_in[3];
    const int*   qkv_qw    = (const int*)  d_in[4];
    const int*   qkv_qz    = (const int*)  d_in[5];
    const float* qkv_sc    = (const float*)d_in[6];
    const int*   o_qw      = (const int*)  d_in[7];
    const int*   o_qz      = (const int*)  d_in[8];
    const float* o_sc      = (const float*)d_in[9];
    const int*   gate_qw   = (const int*)  d_in[10];
    const int*   gate_qz   = (const int*)  d_in[11];
    const float* gate_sc   = (const float*)d_in[12];
    const int*   up_qw     = (const int*)  d_in[13];
    const int*   up_qz     = (const int*)  d_in[14];
    const float* up_sc     = (const float*)d_in[15];
    const int*   down_qw   = (const int*)  d_in[16];
    const int*   down_qz   = (const int*)  d_in[17];
    const float* down_sc   = (const float*)d_in[18];

    char* ws = (char*)d_ws;
    const size_t MB = 1 << 20;
    unsigned short* Wt    = (unsigned short*)(ws + 0);          // weight region
    unsigned short* Wu    = (unsigned short*)(ws + 86 * MB);    // up weights
    unsigned short* xln   = (unsigned short*)(ws + 176 * MB);   // 8 MiB
    unsigned short* qkvb  = (unsigned short*)(ws + 184 * MB);   // 24 MiB
    unsigned short* Qrp   = (unsigned short*)(ws + 208 * MB);   // 8 MiB
    unsigned short* Krp   = (unsigned short*)(ws + 216 * MB);   // 8 MiB
    unsigned short* Vtp   = (unsigned short*)(ws + 224 * MB);   // 8 MiB
    unsigned short* attnb = (unsigned short*)(ws + 232 * MB);   // 8 MiB
    float*          hid   = (float*)        (ws + 240 * MB);    // 16 MiB -> peak 256 MiB
    unsigned short* x2    = xln;
    unsigned short* gateb = qkvb;                               // 22 MiB
    unsigned short* upb   = Qrp;                                // 22 MiB (Q/K/V dead)

    // --- attention block ---
    dequant_kernel<<<dim3(48, 64), 256, 0, stream>>>(qkv_qw, qkv_qz, qkv_sc, Wt, 1536, 4096);
    rmsnorm_kernel<<<1024, 256, 0, stream>>>(hidden, ln1, xln);
    bt_gemm<0><<<dim3(96, 8), 256, 0, stream>>>(xln, Wt, nullptr,
                                                (void*)qkvb, nullptr, nullptr, 12288, 4096);
    rope_kernel<<<1024, 256, 0, stream>>>(positions, qkvb, Qrp, Krp, Vtp);
    dequant_kernel<<<dim3(16, 64), 256, 0, stream>>>(o_qw, o_qz, o_sc, Wt, 512, 4096);
    attn_kernel<<<dim3(16, 32), 256, 0, stream>>>(Qrp, Krp, Vtp, attnb);
    bt_gemm<3><<<dim3(32, 8), 256, 0, stream>>>(attnb, Wt, nullptr,
                                                (void*)hid, nullptr, hidden, 4096, 4096);
    // --- MLP block ---
    rmsnorm_kernel<<<1024, 256, 0, stream>>>(hid, ln2, x2);
    dequant_kernel<<<dim3(43, 64), 256, 0, stream>>>(gate_qw, gate_qz, gate_sc, Wt, 1376, 4096);
    dequant_kernel<<<dim3(43, 64), 256, 0, stream>>>(up_qw, up_qz, up_sc, Wu, 1376, 4096);
    bt_gemm<1><<<dim3(86, 8, 2), 256, 0, stream>>>(x2, Wt, Wu,
                                                   (void*)gateb, (void*)upb, nullptr, 11008, 4096);
    silu_mul_kernel<<<5504, 256, 0, stream>>>(gateb, upb);
    dequant_kernel<<<dim3(16, 172), 256, 0, stream>>>(down_qw, down_qz, down_sc, Wt, 512, 11008);
    bt_gemm<3><<<dim3(32, 8), 256, 0, stream>>>(upb, Wt, nullptr,
                                                d_out, nullptr, hid, 4096, 11008);
}

// Round 9
// 741.346 us; speedup vs baseline: 1.2073x; 1.0817x over previous
//
#include <hip/hip_runtime.h>
#include <cstdint>

// ---------------------------------------------------------------------------
// Types & helpers
// ---------------------------------------------------------------------------
typedef __attribute__((ext_vector_type(8))) short  bf16x8;   // 8 bf16 = 4 VGPR
typedef __attribute__((ext_vector_type(4))) float  f32x4;
typedef __attribute__((ext_vector_type(4))) unsigned int uint4v;
typedef __attribute__((ext_vector_type(2))) unsigned int uint2v;

typedef const __attribute__((address_space(1))) void* gas_t;
typedef __attribute__((address_space(3))) void* las_t;

__device__ __forceinline__ float bf2f(unsigned short b) {
    union { unsigned int u; float f; } v; v.u = ((unsigned int)b) << 16; return v.f;
}
__device__ __forceinline__ unsigned short f2bf(float f) {
    union { float f; unsigned int u; } v; v.f = f;
    unsigned int r = v.u + 0x7FFFu + ((v.u >> 16) & 1u);   // RNE
    return (unsigned short)(r >> 16);
}
__device__ __forceinline__ float u2f(unsigned int u) {
    union { unsigned int u; float f; } v; v.u = u; return v.f;
}

// ---------------------------------------------------------------------------
// Weight dequant + transpose:  packed qw[K][N/8] int4  ->  Wt[N][K] bf16
// ---------------------------------------------------------------------------
__global__ __launch_bounds__(256)
void dequant_kernel(const int* __restrict__ qw, const int* __restrict__ qz,
                    const float* __restrict__ sc, unsigned short* __restrict__ out,
                    int NW, int K)
{
    const int t   = threadIdx.x;
    const int wcb = blockIdx.x << 5;
    const int kb  = blockIdx.y << 6;
    const int g   = blockIdx.y >> 1;          // AWQ group (G=128)
    const int N   = NW << 3;
    const int wc  = wcb + (t >> 3);
    const int k0  = kb + ((t & 7) << 3);

    unsigned int w[8];
#pragma unroll
    for (int j = 0; j < 8; j++) w[j] = (unsigned int)qw[(size_t)(k0 + j) * NW + wc];
    const unsigned int zw = (unsigned int)qz[(size_t)g * NW + wc];
    float scv[8];
#pragma unroll
    for (int j2 = 0; j2 < 8; j2++) scv[j2] = sc[(size_t)g * N + (wc << 3) + j2];

#pragma unroll
    for (int j2 = 0; j2 < 8; j2++) {
        const int sh = j2 << 2;
        const float s = scv[j2];
        const float moff = -(8388608.0f + (float)((zw >> sh) & 0xFu)) * s;
        unsigned int pk[4];
#pragma unroll
        for (int i = 0; i < 4; i++) {
            float f0 = fmaf(u2f(((w[2*i]   >> sh) & 0xFu) | 0x4B000000u), s, moff);
            float f1 = fmaf(u2f(((w[2*i+1] >> sh) & 0xFu) | 0x4B000000u), s, moff);
            asm("v_cvt_pk_bf16_f32 %0, %1, %2" : "=v"(pk[i]) : "v"(f0), "v"(f1));
        }
        uint4v ov = {pk[0], pk[1], pk[2], pk[3]};
        *(uint4v*)(out + (size_t)((wc << 3) + j2) * K + k0) = ov;
    }
}

// ---------------------------------------------------------------------------
// RMSNorm: fp32 [T,4096] -> bf16 [T,4096]
// ---------------------------------------------------------------------------
__global__ __launch_bounds__(256)
void rmsnorm_kernel(const float* __restrict__ x, const float* __restrict__ wgt,
                    unsigned short* __restrict__ out)
{
    const int t = blockIdx.x, tid = threadIdx.x;
    const float4* xr = (const float4*)(x + (size_t)t * 4096);
    float4 v[4];
    float ss = 0.f;
#pragma unroll
    for (int j = 0; j < 4; j++) {
        v[j] = xr[(j << 8) + tid];
        ss += v[j].x*v[j].x + v[j].y*v[j].y + v[j].z*v[j].z + v[j].w*v[j].w;
    }
#pragma unroll
    for (int m = 1; m < 64; m <<= 1) ss += __shfl_xor(ss, m);
    __shared__ float red[4];
    if ((tid & 63) == 0) red[tid >> 6] = ss;
    __syncthreads();
    float tot = red[0] + red[1] + red[2] + red[3];
    float rs = rsqrtf(tot * (1.f / 4096.f) + 1e-6f);
    const float4* wr = (const float4*)wgt;
#pragma unroll
    for (int j = 0; j < 4; j++) {
        float4 wv = wr[(j << 8) + tid];
        float4 xv = v[j];
        unsigned int p0 = (unsigned int)f2bf(xv.x*rs*wv.x) | ((unsigned int)f2bf(xv.y*rs*wv.y) << 16);
        unsigned int p1 = (unsigned int)f2bf(xv.z*rs*wv.z) | ((unsigned int)f2bf(xv.w*rs*wv.w) << 16);
        uint2v pk = {p0, p1};
        *(uint2v*)(&out[(size_t)t*4096 + (size_t)(((j << 8) + tid) << 2)]) = pk;
    }
}

// ---------------------------------------------------------------------------
// Pure bf16 B^T GEMM, m97 structure + XCD-clustered block mapping (T1):
//   flat -> xcd=flat&7, m=(flat>>3)&7, n=((flat>>6)<<3)+xcd
// Per XCD, consecutive blocks sweep the 8 M-blocks of ONE N-panel (B subtile
// hits L2 8x), and XCDs own disjoint N-panel residues (no cross-XCD dup).
// Tile 128x128, BK=64, 256 thr = 4 waves, single-buffer 32KB LDS, 4 blk/CU.
// MODE 0: bf16 out. MODE 3: f32 out = acc + res. MODE 4: bf16 = silu(acc)*aux.
// ---------------------------------------------------------------------------
template<int MODE>
__global__ __launch_bounds__(256, 4)
void bt_gemm(const unsigned short* __restrict__ A,
             const unsigned short* __restrict__ Bt,
             void* __restrict__ out0, const void* __restrict__ aux,
             int N, int K, int NB)
{
    const int flat = blockIdx.x;
    const int nb   = (((flat >> 6) << 3)) + (flat & 7);
    if (nb >= NB) return;
    const int m0 = ((flat >> 3) & 7) << 7;
    const int n0 = nb << 7;

    __shared__ unsigned short As[128 * 64];   // 16KB
    __shared__ unsigned short Bs[128 * 64];   // 16KB

    const int tid  = threadIdx.x;
    const int lane = tid & 63;
    const int wid  = tid >> 6;
    const int wm   = wid >> 1, wn = wid & 1;

    f32x4 acc[4][4];
#pragma unroll
    for (int i = 0; i < 4; i++)
#pragma unroll
        for (int j = 0; j < 4; j++) { f32x4 zv = {0.f,0.f,0.f,0.f}; acc[i][j] = zv; }

    const int nsteps = K >> 6;
    for (int t = 0; t < nsteps; t++) {
        const int k0 = t << 6;
        __syncthreads();   // previous tile's reads complete
#pragma unroll
        for (int i = 0; i < 4; i++) {
            int slot = (i << 8) + tid;          // 0..1023
            int row = slot >> 3, s = slot & 7;
            __builtin_amdgcn_global_load_lds(
                (gas_t)(A + (size_t)(m0 + row) * K + k0 + ((s ^ (row & 7)) << 3)),
                (las_t)&As[slot << 3], 16, 0, 0);
        }
#pragma unroll
        for (int i = 0; i < 4; i++) {
            int slot = (i << 8) + tid;
            int row = slot >> 3, s = slot & 7;
            __builtin_amdgcn_global_load_lds(
                (gas_t)(Bt + (size_t)(n0 + row) * K + k0 + ((s ^ (row & 7)) << 3)),
                (las_t)&Bs[slot << 3], 16, 0, 0);
        }
        __syncthreads();   // drains vmcnt: tile resident
#pragma unroll
        for (int kk = 0; kk < 2; kk++) {
            const int srow = (kk << 2) + (lane >> 4);
            bf16x8 af[4], bfv[4];
#pragma unroll
            for (int mi = 0; mi < 4; mi++) {
                int r = (wm << 6) + (mi << 4) + (lane & 15);
                af[mi] = *(const bf16x8*)(&As[(r << 6) + ((srow ^ (r & 7)) << 3)]);
            }
#pragma unroll
            for (int ni = 0; ni < 4; ni++) {
                int r = (wn << 6) + (ni << 4) + (lane & 15);
                bfv[ni] = *(const bf16x8*)(&Bs[(r << 6) + ((srow ^ (r & 7)) << 3)]);
            }
#pragma unroll
            for (int mi = 0; mi < 4; mi++)
#pragma unroll
                for (int ni = 0; ni < 4; ni++)
                    acc[mi][ni] = __builtin_amdgcn_mfma_f32_16x16x32_bf16(af[mi], bfv[ni], acc[mi][ni], 0, 0, 0);
        }
    }

    // epilogue: C/D layout col=lane&15, row=(lane>>4)*4+reg
    const int rbase = m0 + (wm << 6) + ((lane >> 4) << 2);
    const int cbase = n0 + (wn << 6) + (lane & 15);
#pragma unroll
    for (int mi = 0; mi < 4; mi++) {
#pragma unroll
        for (int r = 0; r < 4; r++) {
            int row = rbase + (mi << 4) + r;
#pragma unroll
            for (int ni = 0; ni < 4; ni++) {
                int col = cbase + (ni << 4);
                float v = acc[mi][ni][r];
                if (MODE == 3) {
                    ((float*)out0)[(size_t)row * N + col] =
                        v + ((const float*)aux)[(size_t)row * N + col];
                } else if (MODE == 4) {
                    float u = bf2f(((const unsigned short*)aux)[(size_t)row * N + col]);
                    float sv = v / (1.f + __expf(-v)) * u;
                    ((unsigned short*)out0)[(size_t)row * N + col] = f2bf(sv);
                } else {
                    ((unsigned short*)out0)[(size_t)row * N + col] = f2bf(v);
                }
            }
        }
    }
}

// ---------------------------------------------------------------------------
// RoPE + layout glue
// ---------------------------------------------------------------------------
__global__ __launch_bounds__(256)
void rope_kernel(const int* __restrict__ positions, const unsigned short* __restrict__ qkv,
                 unsigned short* __restrict__ Qr, unsigned short* __restrict__ Kr,
                 unsigned short* __restrict__ Vtp)
{
    const int t = blockIdx.x, tid = threadIdx.x;
    const float p = (float)positions[t];
    const unsigned short* row = qkv + (size_t)t * 12288;
#pragma unroll 4
    for (int it = 0; it < 16; it++) {
        int task = (it << 8) + tid;
        int i   = task & 63;
        int hh  = (task >> 6) & 31;
        int isK = task >> 11;
        float fr = p * __expf(-(float)i * 0.14391156831f);
        float s, c;
        __sincosf(fr, &s, &c);
        const unsigned short* src = row + (isK << 12) + (hh << 7);
        float x1 = bf2f(src[i]);
        float x2 = bf2f(src[64 + i]);
        float o1 = x1 * c - x2 * s;
        float o2 = x2 * c + x1 * s;
        if (!isK) { o1 *= 0.08838834764831845f; o2 *= 0.08838834764831845f; }
        unsigned short* dst = (isK ? Kr : Qr) + ((size_t)hh * 1024 + t) * 128;
        dst[i]      = f2bf(o1);
        dst[64 + i] = f2bf(o2);
    }
#pragma unroll 4
    for (int it = 0; it < 16; it++) {
        int task = (it << 8) + tid;
        int d = task & 127, hh = task >> 7;
        Vtp[((size_t)hh * 128 + d) * 1024 + t] = row[8192 + task];
    }
}

// ---------------------------------------------------------------------------
// Flash attention (causal). Block = (qt, head). 4 waves x 16 q-rows.
// ---------------------------------------------------------------------------
__global__ __launch_bounds__(256, 2)
void attn_kernel(const unsigned short* __restrict__ Qr, const unsigned short* __restrict__ Kr,
                 const unsigned short* __restrict__ Vtp, unsigned short* __restrict__ attn_out)
{
    __shared__ unsigned short Ks[64 * 128];
    __shared__ unsigned short Vs[128 * 64];
    __shared__ unsigned short Ps[4][16 * 64];
    const int tid = threadIdx.x, lane = tid & 63, w = tid >> 6;
    const int qt = blockIdx.x, h = blockIdx.y;

    const unsigned short* Qh = Qr + ((size_t)h * 1024 + (size_t)qt * 64) * 128;

    bf16x8 qf[4];
#pragma unroll
    for (int kk = 0; kk < 4; kk++)
        qf[kk] = *(const bf16x8*)(Qh + (size_t)((w << 4) + (lane & 15)) * 128 + (kk << 5) + ((lane >> 4) << 3));

    f32x4 o[8];
#pragma unroll
    for (int i = 0; i < 8; i++) { f32x4 zf = {0.f,0.f,0.f,0.f}; o[i] = zf; }
    float Mr[4] = {-1e30f, -1e30f, -1e30f, -1e30f};
    float Lr[4] = {0.f, 0.f, 0.f, 0.f};
    const int qrow0 = (qt << 6) + (w << 4) + ((lane >> 4) << 2);

    for (int kt = 0; kt <= qt; kt++) {
        __syncthreads();
#pragma unroll
        for (int j = 0; j < 4; j++) {
            int slot = (j << 8) + tid;
            int rw = slot >> 4, s = slot & 15;
            int ssrc = (s & 8) | ((s ^ (rw & 7)) & 7);
            const uint4v* src = (const uint4v*)(Kr + ((size_t)h * 1024 + (size_t)kt * 64 + rw) * 128 + (ssrc << 3));
            *(uint4v*)(&Ks[(rw << 7) + (s << 3)]) = *src;
        }
#pragma unroll
        for (int j = 0; j < 4; j++) {
            int slot = (j << 8) + tid;
            int rw = slot >> 3, s = slot & 7;
            const uint4v* src = (const uint4v*)(Vtp + ((size_t)h * 128 + rw) * 1024 + (kt << 6) + ((s ^ (rw & 7)) << 3));
            *(uint4v*)(&Vs[(rw << 6) + (s << 3)]) = *src;
        }
        __syncthreads();

        f32x4 sc4[4];
#pragma unroll
        for (int ni = 0; ni < 4; ni++) { f32x4 zf = {0.f,0.f,0.f,0.f}; sc4[ni] = zf; }
#pragma unroll
        for (int kk = 0; kk < 4; kk++) {
#pragma unroll
            for (int ni = 0; ni < 4; ni++) {
                int r = (ni << 4) + (lane & 15);
                int s = (kk << 2) + (lane >> 4);
                int sp = (s & 8) | ((s ^ (r & 7)) & 7);
                bf16x8 kf = *(const bf16x8*)(&Ks[(r << 7) + (sp << 3)]);
                sc4[ni] = __builtin_amdgcn_mfma_f32_16x16x32_bf16(qf[kk], kf, sc4[ni], 0, 0, 0);
            }
        }

#pragma unroll
        for (int r = 0; r < 4; r++) {
            int qg = qrow0 + r;
            float mx = -1e30f;
#pragma unroll
            for (int ni = 0; ni < 4; ni++) {
                int kg_ = (kt << 6) + (ni << 4) + (lane & 15);
                float v = sc4[ni][r];
                if (kt == qt && kg_ > qg) { v = -1e30f; sc4[ni][r] = v; }
                mx = fmaxf(mx, v);
            }
#pragma unroll
            for (int m_ = 1; m_ < 16; m_ <<= 1) mx = fmaxf(mx, __shfl_xor(mx, m_));
            float mnew  = fmaxf(Mr[r], mx);
            float alpha = __expf(Mr[r] - mnew);
            Mr[r] = mnew;
            float rs = 0.f;
#pragma unroll
            for (int ni = 0; ni < 4; ni++) {
                float pv = __expf(sc4[ni][r] - mnew);
                sc4[ni][r] = pv;
                rs += pv;
            }
#pragma unroll
            for (int m_ = 1; m_ < 16; m_ <<= 1) rs += __shfl_xor(rs, m_);
            Lr[r] = Lr[r] * alpha + rs;
#pragma unroll
            for (int nd = 0; nd < 8; nd++) o[nd][r] *= alpha;
        }

#pragma unroll
        for (int r = 0; r < 4; r++) {
            int qr = ((lane >> 4) << 2) + r;
#pragma unroll
            for (int ni = 0; ni < 4; ni++) {
                int col = (ni << 4) + (lane & 15);
                int phys = (col >> 3) ^ (qr & 7);
                Ps[w][(qr << 6) + (phys << 3) + (col & 7)] = f2bf(sc4[ni][r]);
            }
        }
#pragma unroll
        for (int kk2 = 0; kk2 < 2; kk2++) {
            int rowp = lane & 15;
            int sl = (kk2 << 2) + (lane >> 4);
            bf16x8 pa = *(const bf16x8*)(&Ps[w][(rowp << 6) + ((sl ^ (rowp & 7)) << 3)]);
#pragma unroll
            for (int nd = 0; nd < 8; nd++) {
                int rv = (nd << 4) + (lane & 15);
                bf16x8 vb = *(const bf16x8*)(&Vs[(rv << 6) + ((sl ^ (rv & 7)) << 3)]);
                o[nd] = __builtin_amdgcn_mfma_f32_16x16x32_bf16(pa, vb, o[nd], 0, 0, 0);
            }
        }
    }

#pragma unroll
    for (int r = 0; r < 4; r++) {
        float inv = 1.0f / Lr[r];
        int trow = qrow0 + r;
#pragma unroll
        for (int nd = 0; nd < 8; nd++) {
            int col = (h << 7) + (nd << 4) + (lane & 15);
            attn_out[(size_t)trow * 4096 + col] = f2bf(o[nd][r] * inv);
        }
    }
}

// ---------------------------------------------------------------------------
// Launcher
// ---------------------------------------------------------------------------
extern "C" void kernel_launch(void* const* d_in, const int* in_sizes, int n_in,
                              void* d_out, int out_size, void* d_ws, size_t ws_size,
                              hipStream_t stream)
{
    const int*   positions = (const int*)  d_in[0];
    const float* hidden    = (const float*)d_in[1];
    const float* ln1       = (const float*)d_in[2];
    const float* ln2       = (const float*)d_in[3];
    const int*   qkv_qw    = (const int*)  d_in[4];
    const int*   qkv_qz    = (const int*)  d_in[5];
    const float* qkv_sc    = (const float*)d_in[6];
    const int*   o_qw      = (const int*)  d_in[7];
    const int*   o_qz      = (const int*)  d_in[8];
    const float* o_sc      = (const float*)d_in[9];
    const int*   gate_qw   = (const int*)  d_in[10];
    const int*   gate_qz   = (const int*)  d_in[11];
    const float* gate_sc   = (const float*)d_in[12];
    const int*   up_qw     = (const int*)  d_in[13];
    const int*   up_qz     = (const int*)  d_in[14];
    const float* up_sc     = (const float*)d_in[15];
    const int*   down_qw   = (const int*)  d_in[16];
    const int*   down_qz   = (const int*)  d_in[17];
    const float* down_sc   = (const float*)d_in[18];

    char* ws = (char*)d_ws;
    const size_t MB = 1 << 20;
    unsigned short* Wt    = (unsigned short*)(ws + 0);          // weight region (<=96 MiB)
    unsigned short* Wu    = (unsigned short*)(ws + 86 * MB);    // up weights (86 MiB)
    unsigned short* xln   = (unsigned short*)(ws + 176 * MB);   // 8 MiB
    unsigned short* qkvb  = (unsigned short*)(ws + 184 * MB);   // 24 MiB
    unsigned short* Qrp   = (unsigned short*)(ws + 208 * MB);   // 8 MiB
    unsigned short* Krp   = (unsigned short*)(ws + 216 * MB);   // 8 MiB
    unsigned short* Vtp   = (unsigned short*)(ws + 224 * MB);   // 8 MiB
    unsigned short* attnb = (unsigned short*)(ws + 232 * MB);   // 8 MiB
    float*          hid   = (float*)        (ws + 240 * MB);    // 16 MiB -> peak 256 MiB
    unsigned short* x2    = xln;
    unsigned short* gateb = qkvb;                               // 22 MiB (silu(g)*u)
    unsigned short* upb   = Qrp;                                // 22 MiB (Q/K/V dead)

    // --- attention block ---
    dequant_kernel<<<dim3(48, 64), 256, 0, stream>>>(qkv_qw, qkv_qz, qkv_sc, Wt, 1536, 4096);
    rmsnorm_kernel<<<1024, 256, 0, stream>>>(hidden, ln1, xln);
    bt_gemm<0><<<768, 256, 0, stream>>>(xln, Wt, (void*)qkvb, nullptr, 12288, 4096, 96);
    rope_kernel<<<1024, 256, 0, stream>>>(positions, qkvb, Qrp, Krp, Vtp);
    dequant_kernel<<<dim3(16, 64), 256, 0, stream>>>(o_qw, o_qz, o_sc, Wt, 512, 4096);
    attn_kernel<<<dim3(16, 32), 256, 0, stream>>>(Qrp, Krp, Vtp, attnb);
    bt_gemm<3><<<256, 256, 0, stream>>>(attnb, Wt, (void*)hid, hidden, 4096, 4096, 32);
    // --- MLP block ---
    rmsnorm_kernel<<<1024, 256, 0, stream>>>(hid, ln2, x2);
    dequant_kernel<<<dim3(43, 64), 256, 0, stream>>>(up_qw, up_qz, up_sc, Wu, 1376, 4096);
    bt_gemm<0><<<704, 256, 0, stream>>>(x2, Wu, (void*)upb, nullptr, 11008, 4096, 86);
    dequant_kernel<<<dim3(43, 64), 256, 0, stream>>>(gate_qw, gate_qz, gate_sc, Wt, 1376, 4096);
    bt_gemm<4><<<704, 256, 0, stream>>>(x2, Wt, (void*)gateb, upb, 11008, 4096, 86);
    dequant_kernel<<<dim3(16, 172), 256, 0, stream>>>(down_qw, down_qz, down_sc, Wt, 512, 11008);
    bt_gemm<3><<<256, 256, 0, stream>>>(gateb, Wt, d_out, hid, 4096, 11008, 32);
}